// Round 12
// baseline (565.816 us; speedup 1.0000x reference)
//
#include <hip/hip_runtime.h>
#include <math.h>

#define DEV __device__ __forceinline__

// B=4, S=1024, F=20, D=512, H=8, L=4, FF=2048, M=32, NH=3, D2=256, O=1, HD=64
constexpr int BSD = 4 * 1024 * 512;  // B*S*D

typedef __attribute__((ext_vector_type(8))) short bf16x8;
typedef __attribute__((ext_vector_type(4))) float f32x4;

typedef __attribute__((address_space(1))) const void global_cvoid;
typedef __attribute__((address_space(3))) void lds_void;

DEV ushort f2b(float f) {
  union { float f; uint u; } x{f};
  uint r = x.u + 0x7fff + ((x.u >> 16) & 1);
  return (ushort)(r >> 16);
}
DEV float b2f(ushort u) {
  union { uint u; float f; } x{(uint)u << 16};
  return x.f;
}
DEV int swz128(int b) { return b ^ (((b >> 7) & 7) << 4); }

DEV float wave_sum(float v) {
#pragma unroll
  for (int m = 32; m >= 1; m >>= 1) v += __shfl_xor(v, m, 64);
  return v;
}
DEV float wave_max(float v) {
#pragma unroll
  for (int m = 32; m >= 1; m >>= 1) v = fmaxf(v, __shfl_xor(v, m, 64));
  return v;
}
DEV float block_sum(float v, float* sm) {
  v = wave_sum(v);
  __syncthreads();
  if ((threadIdx.x & 63) == 0) sm[threadIdx.x >> 6] = v;
  __syncthreads();
  return sm[0] + sm[1] + sm[2] + sm[3];
}
DEV float block_max(float v, float* sm) {
  v = wave_max(v);
  __syncthreads();
  if ((threadIdx.x & 63) == 0) sm[threadIdx.x >> 6] = v;
  __syncthreads();
  return fmaxf(fmaxf(sm[0], sm[1]), fmaxf(sm[2], sm[3]));
}

// ---------------------------------------------------------------------------
// Input projection, wave-per-row: h = LN(x @ in_W + in_b)*g + b + posenc
// grid 1024 x 256 threads (4 waves = 4 rows), shfl-only reductions.
// ---------------------------------------------------------------------------
__global__ __launch_bounds__(256) void k_inproj(
    const float* __restrict__ x, const float* __restrict__ W,
    const float* __restrict__ bias, const float* __restrict__ g,
    const float* __restrict__ bt, float* __restrict__ h) {
  int lane = threadIdx.x & 63;
  int r = blockIdx.x * 4 + (threadIdx.x >> 6);
  int s = r & 1023;
  float xr[20];
#pragma unroll
  for (int f = 0; f < 20; f++) xr[f] = x[r * 20 + f];  // wave-uniform
  float o[8];
#pragma unroll
  for (int j = 0; j < 8; j++) {
    int c = lane + 64 * j;
    float acc = bias[c];
#pragma unroll
    for (int f = 0; f < 20; f++) acc += xr[f] * W[f * 512 + c];
    o[j] = acc;
  }
  float ssum = 0.f;
#pragma unroll
  for (int j = 0; j < 8; j++) ssum += o[j];
  float mean = wave_sum(ssum) * (1.f / 512.f);
  float vs = 0.f;
#pragma unroll
  for (int j = 0; j < 8; j++) {
    o[j] -= mean;
    vs += o[j] * o[j];
  }
  float var = wave_sum(vs) * (1.f / 512.f);
  float rs = rsqrtf(var + 1e-5f);
  const float c1 = -9.210340371976184f / 512.f;
#pragma unroll
  for (int j = 0; j < 8; j++) {
    int c = lane + 64 * j;
    float n = o[j] * rs * g[c] + bt[c];
    float div = __expf((float)(c & ~1) * c1);
    float arg = (float)s * div;
    n += (c & 1) ? __cosf(arg) : __sinf(arg);
    h[(size_t)r * 512 + c] = n;
  }
}

// ---------------------------------------------------------------------------
// LayerNorm fp32 -> bf16, one wave per row (shfl-only), 4 rows/block.
// ---------------------------------------------------------------------------
__global__ __launch_bounds__(256) void k_lnw(
    const float* __restrict__ x, const float* __restrict__ g,
    const float* __restrict__ bt, ushort* __restrict__ y) {
  int lane = threadIdx.x & 63;
  int r = blockIdx.x * 4 + (threadIdx.x >> 6);
  const float4* xr = (const float4*)(x + (size_t)r * 512);
  float4 a = xr[lane];
  float4 c = xr[lane + 64];
  float s = a.x + a.y + a.z + a.w + c.x + c.y + c.z + c.w;
  float mean = wave_sum(s) * (1.f / 512.f);
  float d0 = a.x - mean, d1 = a.y - mean, d2 = a.z - mean, d3 = a.w - mean;
  float e0 = c.x - mean, e1 = c.y - mean, e2 = c.z - mean, e3 = c.w - mean;
  float vs = d0 * d0 + d1 * d1 + d2 * d2 + d3 * d3 +
             e0 * e0 + e1 * e1 + e2 * e2 + e3 * e3;
  float var = wave_sum(vs) * (1.f / 512.f);
  float rs = rsqrtf(var + 1e-5f);
  const float4* g4 = (const float4*)g;
  const float4* b4 = (const float4*)bt;
  float4 g0 = g4[lane], g1 = g4[lane + 64];
  float4 b0 = b4[lane], b1 = b4[lane + 64];
  ushort4 o0 = {f2b(d0 * rs * g0.x + b0.x), f2b(d1 * rs * g0.y + b0.y),
                f2b(d2 * rs * g0.z + b0.z), f2b(d3 * rs * g0.w + b0.w)};
  ushort4 o1 = {f2b(e0 * rs * g1.x + b1.x), f2b(e1 * rs * g1.y + b1.y),
                f2b(e2 * rs * g1.z + b1.z), f2b(e3 * rs * g1.w + b1.w)};
  ushort4* yr = (ushort4*)(y + (size_t)r * 512);
  yr[lane] = o0;
  yr[lane + 64] = o1;
}

// ---------------------------------------------------------------------------
// Weight prep: transpose+convert src[K][N] f32 -> dst[N][K] bf16, job table.
// ---------------------------------------------------------------------------
struct PJobs {
  const float* s[19];
  ushort* d[19];
};
__global__ __launch_bounds__(256) void k_wprep(PJobs j, int K, int N) {
  const float* src = j.s[blockIdx.z];
  ushort* dst = j.d[blockIdx.z];
  __shared__ float ld[32][33];
  int n0 = blockIdx.x * 32, k0 = blockIdx.y * 32;
  int c = threadIdx.x & 31, r0 = threadIdx.x >> 5;
#pragma unroll
  for (int i = 0; i < 4; i++)
    ld[r0 + i * 8][c] = src[(size_t)(k0 + r0 + i * 8) * N + n0 + c];
  __syncthreads();
#pragma unroll
  for (int i = 0; i < 4; i++)
    dst[(size_t)(n0 + r0 + i * 8) * K + k0 + c] = f2b(ld[c][r0 + i * 8]);
}

// rel [L][65][64] f32 -> [L][80][64] bf16 *8 (compensates Q prescale), pad 0
__global__ __launch_bounds__(256) void k_relprep(const float* __restrict__ rel,
                                                 ushort* __restrict__ relb) {
  int i = blockIdx.x * 256 + threadIdx.x;  // 0..5119
  int l = blockIdx.y;
  int r = i >> 6, d = i & 63;
  float v = (r < 65) ? rel[((size_t)l * 65 + r) * 64 + d] * 8.f : 0.f;
  relb[(size_t)l * 80 * 64 + i] = f2b(v);
}

// ---------------------------------------------------------------------------
// bf16 MFMA GEMM: double-buffered global_load_lds(16B) + source XOR swizzle,
// issue-next-before-compute (2-phase pipeline), XCD-chunked grid.
// MODE 0: bf16 out; 1: fp32 residual in-place; 2: gelu bf16;
// 3: residual + bf16 copy to C2.
// FUSEB 0: single bias; 1: QKV (3 biases + Q*0.125 + V^T-only write for V);
// 2: KV fused (2 biases).
// ---------------------------------------------------------------------------
template <int BM, int BN, int MODE, int FUSEB>
__global__ __launch_bounds__(256) void k_mg(
    const ushort* __restrict__ A, const ushort* __restrict__ Bt,
    const float* __restrict__ bias0, const float* __restrict__ bias1,
    const float* __restrict__ bias2, void* __restrict__ Cv,
    ushort* __restrict__ C2, int K, int ldc, int gx) {
  __shared__ __align__(16) ushort As[2][BM * 64];
  __shared__ __align__(16) ushort Bs[2][BN * 64];
  int nwg = gridDim.x;
  int id = blockIdx.x;
  int logical = (id & 7) * (nwg >> 3) + (id >> 3);
  int bx = logical % gx, by = logical / gx;
  int row0 = by * BM, col0 = bx * BN;
  int t = threadIdx.x, lane = t & 63, w = t >> 6;
  int rl15 = lane & 15, l16 = lane >> 4;
  constexpr int WR = (BM == 128 && BN == 128) ? 2 : BM / 32;
  constexpr int WC = 4 / WR;
  constexpr int MI = BM / (WR * 16);
  constexpr int NI = BN / (WC * 16);
  int wr = w % WR, wc = w / WR;
  int wrow = wr * MI * 16;
  int wcol = wc * NI * 16;
  f32x4 acc[MI][NI] = {};

  auto stage = [&](int buf, int kb) {
#pragma unroll
    for (int i = 0; i < BM / 32; i++) {
      int blk = w * (BM / 32) + i;
      int lb = blk * 1024 + lane * 16;
      int lg = swz128(lb);
      int r = lg >> 7, cb = (lg & 127) >> 1;
      __builtin_amdgcn_global_load_lds(
          (global_cvoid*)(A + (size_t)(row0 + r) * K + kb + cb),
          (lds_void*)((char*)As[buf] + blk * 1024), 16, 0, 0);
    }
#pragma unroll
    for (int i = 0; i < BN / 32; i++) {
      int blk = w * (BN / 32) + i;
      int lb = blk * 1024 + lane * 16;
      int lg = swz128(lb);
      int r = lg >> 7, cb = (lg & 127) >> 1;
      __builtin_amdgcn_global_load_lds(
          (global_cvoid*)(Bt + (size_t)(col0 + r) * K + kb + cb),
          (lds_void*)((char*)Bs[buf] + blk * 1024), 16, 0, 0);
    }
  };

  stage(0, 0);
  __syncthreads();
  int nkt = K >> 6;
  for (int kt = 0; kt < nkt; kt++) {
    int cur = kt & 1;
    if (kt + 1 < nkt) stage(cur ^ 1, (kt + 1) << 6);
#pragma unroll
    for (int ks = 0; ks < 2; ks++) {
      bf16x8 af[MI], bfr[NI];
#pragma unroll
      for (int mi = 0; mi < MI; mi++) {
        int row = wrow + mi * 16 + rl15;
        af[mi] =
            *(const bf16x8*)((char*)As[cur] + swz128(row * 128 + ks * 64 + l16 * 16));
      }
#pragma unroll
      for (int ni = 0; ni < NI; ni++) {
        int row = wcol + ni * 16 + rl15;
        bfr[ni] =
            *(const bf16x8*)((char*)Bs[cur] + swz128(row * 128 + ks * 64 + l16 * 16));
      }
#pragma unroll
      for (int mi = 0; mi < MI; mi++)
#pragma unroll
        for (int ni = 0; ni < NI; ni++)
          acc[mi][ni] = __builtin_amdgcn_mfma_f32_16x16x32_bf16(af[mi], bfr[ni],
                                                                acc[mi][ni], 0, 0, 0);
    }
    __syncthreads();
  }
#pragma unroll
  for (int mi = 0; mi < MI; mi++) {
#pragma unroll
    for (int ni = 0; ni < NI; ni++) {
      int col = col0 + wcol + ni * 16 + rl15;
      float bv;
      if (FUSEB == 1) {
        const float* bp = bias0;
        int c = col;
        if (c >= 1024) { bp = bias2; c -= 1024; }
        else if (c >= 512) { bp = bias1; c -= 512; }
        bv = bp[c];
      } else if (FUSEB == 2) {
        bv = (col < 512) ? bias0[col] : bias1[col - 512];
      } else {
        bv = bias0[col];
      }
#pragma unroll
      for (int r = 0; r < 4; r++) {
        int row = row0 + wrow + mi * 16 + l16 * 4 + r;
        float val = acc[mi][ni][r] + bv;
        if (FUSEB == 1 && col < 512) val *= 0.125f;  // fold 1/sqrt(HD) into Q
        if (MODE == 0) {
          ushort bval = f2b(val);
          if (FUSEB == 1 && col >= 1024) {
            // V: only the transposed copy is consumed (attn reads vT)
            int dg = col - 1024;
            int bh = (row >> 10) * 8 + (dg >> 6);
            C2[((size_t)bh * 64 + (dg & 63)) * 1024 + (row & 1023)] = bval;
          } else {
            ((ushort*)Cv)[(size_t)row * ldc + col] = bval;
          }
        } else if (MODE == 1) {
          float* Cp = (float*)Cv + (size_t)row * ldc + col;
          *Cp = *Cp + val;
        } else if (MODE == 2) {
          val = 0.5f * val * (1.f + erff(val * 0.70710678118654752f));
          ((ushort*)Cv)[(size_t)row * ldc + col] = f2b(val);
        } else {
          float* Cp = (float*)Cv + (size_t)row * ldc + col;
          float nv = *Cp + val;
          *Cp = nv;
          C2[(size_t)row * ldc + col] = f2b(nv);
        }
      }
    }
  }
}

// ---------------------------------------------------------------------------
// MFMA flash attention v7: in-block split-K (8 waves = 4 q-subtiles x 2
// k-groups), K double-buffered in LDS per group, V^T fragments in REGISTERS
// (early-issued from L2-resident vT), swapped QK^T softmax, defer-max,
// split-K merge via LDS. grid 512 x 512 threads. Q prescaled 1/8, rel *8.
// ---------------------------------------------------------------------------
__global__ __launch_bounds__(512, 4) void k_attn4(
    const ushort* __restrict__ qkv, const ushort* __restrict__ vT,
    const ushort* __restrict__ relb, ushort* __restrict__ ao) {
  __shared__ __align__(16) ushort Ks[2][2][64 * 64];  // [group][buf]
  __shared__ ushort qrlb[4][16][66];
  __shared__ __align__(16) ushort Pl[8][16 * 72];
  __shared__ float Om[4][16][64];
  __shared__ float Ml[4][16][2];
  int t = threadIdx.x, lane = t & 63, w = t >> 6;
  int wq = w & 3, kh = w >> 2;
  int bid = blockIdx.x;
  int p = bid & 31;
  int h = p & 7, b = p >> 3;
  int q0 = (bid >> 5) * 64;
  int qw = q0 + wq * 16;
  int rl15 = lane & 15, l16 = lane >> 4;
  size_t baseq = ((size_t)b * 1024) * 1536 + h * 64;
  size_t basek = baseq + 512;
  const ushort* vTb = vT + ((size_t)(b * 8 + h)) * 64 * 1024;

  bf16x8 aq[2];
#pragma unroll
  for (int ks = 0; ks < 2; ks++)
    aq[ks] = *(const bf16x8*)(qkv + baseq + (size_t)(qw + rl15) * 1536 + ks * 32 + l16 * 8);

  // qrl[qrow][r] = Q'.rel'[r] -- computed by group 0, shared with group 1
  if (kh == 0) {
#pragma unroll
    for (int nb = 0; nb < 5; nb++) {
      f32x4 rc = {};
#pragma unroll
      for (int ks = 0; ks < 2; ks++) {
        bf16x8 rb =
            *(const bf16x8*)(relb + (size_t)(nb * 16 + rl15) * 64 + ks * 32 + l16 * 8);
        rc = __builtin_amdgcn_mfma_f32_16x16x32_bf16(aq[ks], rb, rc, 0, 0, 0);
      }
      int col = nb * 16 + rl15;
      if (col < 65) {
#pragma unroll
        for (int r = 0; r < 4; r++) qrlb[wq][l16 * 4 + r][col] = f2b(rc[r]);
      }
    }
  }

  auto stageK = [&](int buf, int kb) {
#pragma unroll
    for (int i = 0; i < 2; i++) {
      int blk = wq * 2 + i;
      int lb = blk * 1024 + lane * 16;
      int lg = swz128(lb);
      int r = lg >> 7, cb = (lg & 127) >> 1;
      __builtin_amdgcn_global_load_lds(
          (global_cvoid*)(qkv + basek + (size_t)(kb + r) * 1536 + cb),
          (lds_void*)((char*)Ks[kh][buf] + blk * 1024), 16, 0, 0);
    }
  };

  // online-softmax state: lane owns query rl15 (replicated over l16 groups)
  float m_own = -1e30f, l_own = 0.f;
  f32x4 oacc[4] = {};  // PV accum, rows = queries l16*4+r (C-layout)

  stageK(0, kh << 9);
  __syncthreads();

  for (int kt = 0; kt < 8; kt++) {
    int kb = (kh << 9) + (kt << 6);
    int cur = kt & 1;
    if (kt < 7) stageK(cur ^ 1, kb + 64);

    // V^T fragments direct from global (L2) -- early issue, used after softmax
    bf16x8 vf[2][4];
#pragma unroll
    for (int ks = 0; ks < 2; ks++)
#pragma unroll
      for (int nb = 0; nb < 4; nb++)
        vf[ks][nb] = *(const bf16x8*)(vTb + (size_t)(nb * 16 + rl15) * 1024 + kb +
                                      ks * 32 + l16 * 8);

    // S^T = K Q^T : col=rl15=query, row=l16*4+r(+16nb)=key
    f32x4 sacc[4] = {};
#pragma unroll
    for (int ks = 0; ks < 2; ks++) {
#pragma unroll
      for (int nb = 0; nb < 4; nb++) {
        bf16x8 kf = *(const bf16x8*)((char*)Ks[kh][cur] +
                                     swz128((nb * 16 + rl15) * 128 + ks * 64 + l16 * 16));
        sacc[nb] = __builtin_amdgcn_mfma_f32_16x16x32_bf16(kf, aq[ks], sacc[nb], 0, 0, 0);
      }
    }

    // rel add: uniform fast path vs banded path (lane's query = rl15)
    float sv[4][4];
    bool hiU = (kb >= qw + 47);
    bool loU = (kb + 95 <= qw);
    if (hiU || loU) {
      float crow = b2f(qrlb[wq][rl15][hiU ? 64 : 0]);
#pragma unroll
      for (int nb = 0; nb < 4; nb++)
#pragma unroll
        for (int r = 0; r < 4; r++) sv[nb][r] = sacc[nb][r] + crow;
    } else {
      int qg = qw + rl15;
#pragma unroll
      for (int nb = 0; nb < 4; nb++)
#pragma unroll
        for (int r = 0; r < 4; r++) {
          int delta = kb + nb * 16 + l16 * 4 + r - qg;
          delta = delta < -32 ? -32 : (delta > 32 ? 32 : delta);
          sv[nb][r] = sacc[nb][r] + b2f(qrlb[wq][rl15][delta + 32]);
        }
    }

    // row max: 15 local fmax + 2 shfl (across l16 groups)
    float rowm = sv[0][0];
#pragma unroll
    for (int nb = 0; nb < 4; nb++)
#pragma unroll
      for (int r = 0; r < 4; r++) rowm = fmaxf(rowm, sv[nb][r]);
    rowm = fmaxf(rowm, __shfl_xor(rowm, 16, 64));
    rowm = fmaxf(rowm, __shfl_xor(rowm, 32, 64));

    if (__any(rowm > m_own + 8.f)) {  // defer-max THR=8
      float mn = fmaxf(m_own, rowm);
      float sc = __expf(m_own - mn);
      m_own = mn;
      l_own *= sc;
      float s0 = __shfl(sc, l16 * 4 + 0, 64);
      float s1 = __shfl(sc, l16 * 4 + 1, 64);
      float s2 = __shfl(sc, l16 * 4 + 2, 64);
      float s3 = __shfl(sc, l16 * 4 + 3, 64);
#pragma unroll
      for (int nb = 0; nb < 4; nb++) {
        oacc[nb][0] *= s0;
        oacc[nb][1] *= s1;
        oacc[nb][2] *= s2;
        oacc[nb][3] *= s3;
      }
    }

    float pv[4][4];
    float ls = 0.f;
#pragma unroll
    for (int nb = 0; nb < 4; nb++)
#pragma unroll
      for (int r = 0; r < 4; r++) {
        float e = __expf(sv[nb][r] - m_own);
        pv[nb][r] = e;
        ls += e;
      }
    ls += __shfl_xor(ls, 16, 64);
    ls += __shfl_xor(ls, 32, 64);
    l_own += ls;

    // P -> wave-private LDS as [query=rl15][key], paired u32 writes
#pragma unroll
    for (int nb = 0; nb < 4; nb++) {
      uint w0 = (uint)f2b(pv[nb][0]) | ((uint)f2b(pv[nb][1]) << 16);
      uint w1 = (uint)f2b(pv[nb][2]) | ((uint)f2b(pv[nb][3]) << 16);
      uint* dst = (uint*)&Pl[w][rl15 * 72 + nb * 16 + l16 * 4];
      dst[0] = w0;
      dst[1] = w1;
    }
    // PV: A = P (rows=queries), B = V^T register frags
#pragma unroll
    for (int ks = 0; ks < 2; ks++) {
      bf16x8 pa = *(const bf16x8*)&Pl[w][rl15 * 72 + ks * 32 + l16 * 8];
#pragma unroll
      for (int nb = 0; nb < 4; nb++)
        oacc[nb] = __builtin_amdgcn_mfma_f32_16x16x32_bf16(pa, vf[ks][nb],
                                                           oacc[nb], 0, 0, 0);
    }
    __syncthreads();
  }

  // split-K merge: group 1 publishes partials; group 0 combines & writes
  if (kh == 1) {
#pragma unroll
    for (int nb = 0; nb < 4; nb++)
#pragma unroll
      for (int r = 0; r < 4; r++) Om[wq][l16 * 4 + r][nb * 16 + rl15] = oacc[nb][r];
    if (l16 == 0) {
      Ml[wq][rl15][0] = m_own;
      Ml[wq][rl15][1] = l_own;
    }
  }
  __syncthreads();
  if (kh == 0) {
    size_t baseo = ((size_t)b * 1024) * 512 + h * 64;
#pragma unroll
    for (int r = 0; r < 4; r++) {
      int row = l16 * 4 + r;
      float m1 = __shfl(m_own, row, 64);
      float l1 = __shfl(l_own, row, 64);
      float m2 = Ml[wq][row][0], l2 = Ml[wq][row][1];
      float mn = fmaxf(m1, m2);
      float s1 = __expf(m1 - mn), s2 = __expf(m2 - mn);
      float linv = 1.f / (l1 * s1 + l2 * s2);
#pragma unroll
      for (int nb = 0; nb < 4; nb++) {
        float val = (oacc[nb][r] * s1 + Om[wq][row][nb * 16 + rl15] * s2) * linv;
        ao[baseo + (size_t)(qw + row) * 512 + nb * 16 + rl15] = f2b(val);
      }
    }
  }
}

// ---------------------------------------------------------------------------
// Final global attention v2: computes last-row Q in-kernel (xn @ gWq),
// then streams the KV-only buffer [4096][1024] (k at 0, v at 512).
// ---------------------------------------------------------------------------
__global__ __launch_bounds__(256) void k_gattn2(
    const ushort* __restrict__ xn, const float* __restrict__ gWq,
    const float* __restrict__ gbq, const ushort* __restrict__ kv,
    float* __restrict__ ctxa) {
  int t = threadIdx.x;
  int h = blockIdx.x & 7, b = blockIdx.x >> 3;
  __shared__ float Qs[64];
  __shared__ float qp[4][64];
  __shared__ float sc[1024];
  __shared__ float red[4];
  __shared__ float op[4][64];
  {
    int d = t & 63, q = t >> 6;
    const ushort* xr = xn + (size_t)(b * 1024 + 1023) * 512;
    float acc = 0.f;
    for (int k = q * 128; k < q * 128 + 128; k++)
      acc += b2f(xr[k]) * gWq[(size_t)k * 512 + h * 64 + d];
    qp[q][d] = acc;
  }
  __syncthreads();
  if (t < 64)
    Qs[t] = (qp[0][t] + qp[1][t] + qp[2][t] + qp[3][t] + gbq[h * 64 + t]) * 0.125f;
  __syncthreads();
  float lm = -1e30f;
  float sv[4];
#pragma unroll
  for (int jj = 0; jj < 4; jj++) {
    int j = t + (jj << 8);
    const bf16x8* kp = (const bf16x8*)(kv + (size_t)(b * 1024 + j) * 1024 + h * 64);
    float s = 0.f;
#pragma unroll
    for (int c = 0; c < 8; c++) {
      bf16x8 v8 = kp[c];
#pragma unroll
      for (int e = 0; e < 8; e++) s += Qs[c * 8 + e] * b2f((ushort)v8[e]);
    }
    sv[jj] = s;
    lm = fmaxf(lm, s);
  }
  float bm = block_max(lm, red);
  float ls = 0.f;
#pragma unroll
  for (int jj = 0; jj < 4; jj++) {
    float e = __expf(sv[jj] - bm);
    sc[t + (jj << 8)] = e;
    ls += e;
  }
  float bs = block_sum(ls, red);
  int d = t & 63, qd = t >> 6;
  float acc = 0.f;
  for (int j = qd << 8; j < (qd << 8) + 256; j++)
    acc += sc[j] * b2f(kv[(size_t)(b * 1024 + j) * 1024 + 512 + h * 64 + d]);
  op[qd][d] = acc;
  __syncthreads();
  if (t < 64) {
    float r = (op[0][t] + op[1][t] + op[2][t] + op[3][t]) / bs;
    ctxa[b * 512 + h * 64 + t] = r;
  }
}

// ---------------------------------------------------------------------------
// 4-row GEMM (fp32) parallel: ctx = attnlast @ gWo + gbo.
// ---------------------------------------------------------------------------
__global__ __launch_bounds__(256) void k_rowgemm(
    const float* __restrict__ xrow, const float* __restrict__ W,
    const float* __restrict__ bias, float* __restrict__ y) {
  int b = blockIdx.x >> 4;
  int col0 = (blockIdx.x & 15) * 32;
  int t = threadIdx.x;
  int col = t & 31, kq = t >> 5;  // 8 k-groups of 64
  __shared__ float xs[512];
  __shared__ float part[8][32];
  if (t < 128) ((float4*)xs)[t] = ((const float4*)(xrow + b * 512))[t];
  __syncthreads();
  float acc = 0.f;
  const float* Wp = W + (size_t)(kq * 64) * 512 + col0 + col;
#pragma unroll 8
  for (int k = 0; k < 64; k++) acc += xs[kq * 64 + k] * Wp[(size_t)k * 512];
  part[kq][col] = acc;
  __syncthreads();
  if (t < 32) {
    float s = part[0][t] + part[1][t] + part[2][t] + part[3][t] +
              part[4][t] + part[5][t] + part[6][t] + part[7][t];
    y[b * 512 + col0 + t] = s + bias[col0 + t];
  }
}

// ---------------------------------------------------------------------------
// Head MLP (fp32), 512 threads: 2-way K-split on the D2=256 projection.
// ---------------------------------------------------------------------------
__global__ __launch_bounds__(512) void k_head(
    const float* __restrict__ ctx, const float* __restrict__ hW1,
    const float* __restrict__ hb1, const float* __restrict__ hg,
    const float* __restrict__ hbt, const float* __restrict__ hW2,
    const float* __restrict__ hb2, float* __restrict__ out) {
  int b = blockIdx.x / 3, nh = blockIdx.x % 3;
  int t = threadIdx.x;
  __shared__ float cs[512];
  __shared__ float part[2][256];
  __shared__ float red[8];
  if (t < 128) ((float4*)cs)[t] = ((const float4*)(ctx + b * 512))[t];
  __syncthreads();
  {
    int col = t & 255, kh = t >> 8;
    float acc = 0.f;
    const float* Wp = hW1 + ((size_t)nh * 512 + kh * 256) * 256 + col;
#pragma unroll 8
    for (int d = 0; d < 256; d++) acc += cs[kh * 256 + d] * Wp[(size_t)d * 256];
    part[kh][col] = acc;
  }
  __syncthreads();
  float y = 0.f;
  if (t < 256) y = part[0][t] + part[1][t] + hb1[nh * 256 + t];
  float v = wave_sum(t < 256 ? y : 0.f);
  if ((t & 63) == 0) red[t >> 6] = v;
  __syncthreads();
  float mean = (red[0] + red[1] + red[2] + red[3] + red[4] + red[5] + red[6] +
                red[7]) * (1.f / 256.f);
  float dv = (t < 256) ? (y - mean) : 0.f;
  float v2 = wave_sum(dv * dv);
  __syncthreads();
  if ((t & 63) == 0) red[t >> 6] = v2;
  __syncthreads();
  float var = (red[0] + red[1] + red[2] + red[3] + red[4] + red[5] + red[6] +
               red[7]) * (1.f / 256.f);
  float rs = rsqrtf(var + 1e-5f);
  float yn = 0.f;
  if (t < 256) {
    yn = dv * rs * hg[nh * 256 + t] + hbt[nh * 256 + t];
    yn = fmaxf(yn, 0.f) * hW2[nh * 256 + t];
  }
  float v3 = wave_sum(yn);
  __syncthreads();
  if ((t & 63) == 0) red[t >> 6] = v3;
  __syncthreads();
  if (t == 0) {
    float s = red[0] + red[1] + red[2] + red[3] + red[4] + red[5] + red[6] + red[7];
    out[b * 3 + nh] = s + hb2[nh];
  }
}

// ---------------------------------------------------------------------------
extern "C" void kernel_launch(void* const* d_in, const int* in_sizes, int n_in,
                              void* d_out, int out_size, void* d_ws, size_t ws_size,
                              hipStream_t stream) {
  const float* x = (const float*)d_in[0];
  const float* in_W = (const float*)d_in[1];
  const float* in_b = (const float*)d_in[2];
  const float* in_lng = (const float*)d_in[3];
  const float* in_lnb = (const float*)d_in[4];
  const float* ln1_g = (const float*)d_in[5];
  const float* ln1_b = (const float*)d_in[6];
  const float* Wq = (const float*)d_in[7];
  const float* bq = (const float*)d_in[8];
  const float* Wk = (const float*)d_in[9];
  const float* bk = (const float*)d_in[10];
  const float* Wv = (const float*)d_in[11];
  const float* bv = (const float*)d_in[12];
  const float* Wo = (const float*)d_in[13];
  const float* bo = (const float*)d_in[14];
  const float* rel = (const float*)d_in[15];
  const float* ln2_g = (const float*)d_in[16];
  const float* ln2_b = (const float*)d_in[17];
  const float* W1 = (const float*)d_in[18];
  const float* b1 = (const float*)d_in[19];
  const float* W2 = (const float*)d_in[20];
  const float* b2 = (const float*)d_in[21];
  const float* gWq = (const float*)d_in[22];
  const float* gbq = (const float*)d_in[23];
  const float* gWk = (const float*)d_in[24];
  const float* gbk = (const float*)d_in[25];
  const float* gWv = (const float*)d_in[26];
  const float* gbv = (const float*)d_in[27];
  const float* gWo = (const float*)d_in[28];
  const float* gbo = (const float*)d_in[29];
  const float* hW1 = (const float*)d_in[30];
  const float* hb1 = (const float*)d_in[31];
  const float* hlng = (const float*)d_in[32];
  const float* hlnb = (const float*)d_in[33];
  const float* hW2 = (const float*)d_in[34];
  const float* hb2 = (const float*)d_in[35];
  float* out = (float*)d_out;

  uint8_t* wsb = (uint8_t*)d_ws;
  const size_t MB = 1024 * 1024;
  float* h = (float*)(wsb + 0);              // 8 MB
  ushort* xn = (ushort*)(wsb + 8 * MB);      // 4 MB
  ushort* qkvb = (ushort*)(wsb + 12 * MB);   // 12 MB  [4096][1536]
  ushort* kvb = qkvb;                        // final KV [4096][1024] (reuse)
  ushort* aob = (ushort*)(wsb + 24 * MB);    // 4 MB
  ushort* ffb = (ushort*)(wsb + 28 * MB);    // 16 MB  [4096][2048]
  ushort* vTb = ffb;                         // 4 MB, time-shared with ffb
  ushort* wqkv = (ushort*)(wsb + 44 * MB);   // 4 x 1.5 MB
  ushort* wto = (ushort*)(wsb + 50 * MB);    // 4 x 0.5 MB
  ushort* wt1 = (ushort*)(wsb + 52 * MB);    // 4 x 2 MB
  ushort* wt2 = (ushort*)(wsb + 60 * MB);    // 4 x 2 MB
  ushort* gwkv = (ushort*)(wsb + 68 * MB);   // 1 MB (gWk,gWv transposed)
  ushort* relb = (ushort*)(wsb + 70 * MB);   // 40 KB
  float* attnlast = (float*)(wsb + 71 * MB);
  float* ctx = attnlast + 4096;

  const size_t W55 = 512 * 512;

  // ---- upfront weight prep ----
  {
    PJobs j{};
    for (int l = 0; l < 4; l++) {
      j.s[l * 4 + 0] = Wq + (size_t)l * W55;
      j.d[l * 4 + 0] = wqkv + (size_t)l * 1536 * 512;
      j.s[l * 4 + 1] = Wk + (size_t)l * W55;
      j.d[l * 4 + 1] = wqkv + (size_t)l * 1536 * 512 + 512 * 512;
      j.s[l * 4 + 2] = Wv + (size_t)l * W55;
      j.d[l * 4 + 2] = wqkv + (size_t)l * 1536 * 512 + 1024 * 512;
      j.s[l * 4 + 3] = Wo + (size_t)l * W55;
      j.d[l * 4 + 3] = wto + (size_t)l * W55;
    }
    j.s[16] = gWk; j.d[16] = gwkv;
    j.s[17] = gWv; j.d[17] = gwkv + 512 * 512;
    k_wprep<<<dim3(16, 16, 18), 256, 0, stream>>>(j, 512, 512);
  }
  {
    PJobs j{};
    for (int l = 0; l < 4; l++) {
      j.s[l] = W1 + (size_t)l * 512 * 2048;
      j.d[l] = wt1 + (size_t)l * 2048 * 512;
    }
    k_wprep<<<dim3(64, 16, 4), 256, 0, stream>>>(j, 512, 2048);
  }
  {
    PJobs j{};
    for (int l = 0; l < 4; l++) {
      j.s[l] = W2 + (size_t)l * 2048 * 512;
      j.d[l] = wt2 + (size_t)l * 512 * 2048;
    }
    k_wprep<<<dim3(16, 64, 4), 256, 0, stream>>>(j, 2048, 512);
  }
  k_relprep<<<dim3(20, 4), 256, 0, stream>>>(rel, relb);
  k_inproj<<<1024, 256, 0, stream>>>(x, in_W, in_b, in_lng, in_lnb, h);

  for (int l = 0; l < 4; l++) {
    size_t vo = (size_t)l * 512;
    k_lnw<<<1024, 256, 0, stream>>>(h, ln1_g + vo, ln1_b + vo, xn);
    // fused QKV (V written only as V^T into vTb)
    k_mg<128, 64, 0, 1><<<768, 256, 0, stream>>>(xn, wqkv + (size_t)l * 1536 * 512,
                                                 bq + vo, bk + vo, bv + vo, qkvb,
                                                 vTb, 512, 1536, 24);
    k_attn4<<<512, 512, 0, stream>>>(qkvb, vTb, relb + (size_t)l * 80 * 64, aob);
    k_mg<64, 64, 1, 0><<<512, 256, 0, stream>>>(aob, wto + (size_t)l * W55, bo + vo,
                                                nullptr, nullptr, h, nullptr, 512, 512, 8);
    k_lnw<<<1024, 256, 0, stream>>>(h, ln2_g + vo, ln2_b + vo, xn);
    k_mg<128, 128, 2, 0><<<512, 256, 0, stream>>>(xn, wt1 + (size_t)l * 2048 * 512,
                                                  b1 + (size_t)l * 2048, nullptr, nullptr,
                                                  ffb, nullptr, 512, 2048, 16);
    if (l < 3)
      k_mg<64, 64, 1, 0><<<512, 256, 0, stream>>>(ffb, wt2 + (size_t)l * 512 * 2048,
                                                  b2 + vo, nullptr, nullptr, h, nullptr,
                                                  2048, 512, 8);
    else
      k_mg<64, 64, 3, 0><<<512, 256, 0, stream>>>(ffb, wt2 + (size_t)l * 512 * 2048,
                                                  b2 + vo, nullptr, nullptr, h, xn,
                                                  2048, 512, 8);
  }

  // final global attention: KV-only GEMM + in-kernel Q
  k_mg<128, 64, 0, 2><<<512, 256, 0, stream>>>(xn, gwkv, gbk, gbv, nullptr, kvb,
                                               nullptr, 512, 1024, 16);
  k_gattn2<<<32, 256, 0, stream>>>(xn, gWq, gbq, kvb, attnlast);
  k_rowgemm<<<64, 256, 0, stream>>>(attnlast, gWo, gbo, ctx);
  k_head<<<12, 512, 0, stream>>>(ctx, hW1, hb1, hlng, hlnb, hW2, hb2, out);
}

// Round 13
// 512.306 us; speedup vs baseline: 1.1044x; 1.1044x over previous
//
#include <hip/hip_runtime.h>
#include <math.h>

#define DEV __device__ __forceinline__

// B=4, S=1024, F=20, D=512, H=8, L=4, FF=2048, M=32, NH=3, D2=256, O=1, HD=64
constexpr int BSD = 4 * 1024 * 512;  // B*S*D

typedef __attribute__((ext_vector_type(8))) short bf16x8;
typedef __attribute__((ext_vector_type(4))) float f32x4;

typedef __attribute__((address_space(1))) const void global_cvoid;
typedef __attribute__((address_space(3))) void lds_void;

DEV ushort f2b(float f) {
  union { float f; uint u; } x{f};
  uint r = x.u + 0x7fff + ((x.u >> 16) & 1);
  return (ushort)(r >> 16);
}
DEV float b2f(ushort u) {
  union { uint u; float f; } x{(uint)u << 16};
  return x.f;
}
DEV int swz128(int b) { return b ^ (((b >> 7) & 7) << 4); }

DEV float wave_sum(float v) {
#pragma unroll
  for (int m = 32; m >= 1; m >>= 1) v += __shfl_xor(v, m, 64);
  return v;
}
DEV float wave_max(float v) {
#pragma unroll
  for (int m = 32; m >= 1; m >>= 1) v = fmaxf(v, __shfl_xor(v, m, 64));
  return v;
}
DEV float block_sum(float v, float* sm) {
  v = wave_sum(v);
  __syncthreads();
  if ((threadIdx.x & 63) == 0) sm[threadIdx.x >> 6] = v;
  __syncthreads();
  return sm[0] + sm[1] + sm[2] + sm[3];
}
DEV float block_max(float v, float* sm) {
  v = wave_max(v);
  __syncthreads();
  if ((threadIdx.x & 63) == 0) sm[threadIdx.x >> 6] = v;
  __syncthreads();
  return fmaxf(fmaxf(sm[0], sm[1]), fmaxf(sm[2], sm[3]));
}

// ---------------------------------------------------------------------------
// Input projection, wave-per-row: h = LN(x @ in_W + in_b)*g + b + posenc.
// ALSO fuses layer-0 ln1: xn = bf16(LN(h)*l1g + l1b).
// grid 1024 x 256 threads (4 waves = 4 rows), shfl-only reductions.
// ---------------------------------------------------------------------------
__global__ __launch_bounds__(256) void k_inproj(
    const float* __restrict__ x, const float* __restrict__ W,
    const float* __restrict__ bias, const float* __restrict__ g,
    const float* __restrict__ bt, const float* __restrict__ l1g,
    const float* __restrict__ l1b, float* __restrict__ h,
    ushort* __restrict__ xn) {
  int lane = threadIdx.x & 63;
  int r = blockIdx.x * 4 + (threadIdx.x >> 6);
  int s = r & 1023;
  float xr[20];
#pragma unroll
  for (int f = 0; f < 20; f++) xr[f] = x[r * 20 + f];  // wave-uniform
  float o[8];
#pragma unroll
  for (int j = 0; j < 8; j++) {
    int c = lane + 64 * j;
    float acc = bias[c];
#pragma unroll
    for (int f = 0; f < 20; f++) acc += xr[f] * W[f * 512 + c];
    o[j] = acc;
  }
  float ssum = 0.f;
#pragma unroll
  for (int j = 0; j < 8; j++) ssum += o[j];
  float mean = wave_sum(ssum) * (1.f / 512.f);
  float vs = 0.f;
#pragma unroll
  for (int j = 0; j < 8; j++) {
    o[j] -= mean;
    vs += o[j] * o[j];
  }
  float var = wave_sum(vs) * (1.f / 512.f);
  float rs = rsqrtf(var + 1e-5f);
  const float c1 = -9.210340371976184f / 512.f;
#pragma unroll
  for (int j = 0; j < 8; j++) {
    int c = lane + 64 * j;
    float n = o[j] * rs * g[c] + bt[c];
    float div = __expf((float)(c & ~1) * c1);
    float arg = (float)s * div;
    n += (c & 1) ? __cosf(arg) : __sinf(arg);
    h[(size_t)r * 512 + c] = n;
    o[j] = n;  // keep row for fused ln1
  }
  // fused layer-0 ln1 on the full row held in wave registers
  float s2 = 0.f;
#pragma unroll
  for (int j = 0; j < 8; j++) s2 += o[j];
  float mean2 = wave_sum(s2) * (1.f / 512.f);
  float vs2 = 0.f;
#pragma unroll
  for (int j = 0; j < 8; j++) {
    o[j] -= mean2;
    vs2 += o[j] * o[j];
  }
  float var2 = wave_sum(vs2) * (1.f / 512.f);
  float rs2 = rsqrtf(var2 + 1e-5f);
#pragma unroll
  for (int j = 0; j < 8; j++) {
    int c = lane + 64 * j;
    xn[(size_t)r * 512 + c] = f2b(o[j] * rs2 * l1g[c] + l1b[c]);
  }
}

// ---------------------------------------------------------------------------
// LayerNorm fp32 -> bf16, one wave per row (shfl-only), 4 rows/block.
// ---------------------------------------------------------------------------
__global__ __launch_bounds__(256) void k_lnw(
    const float* __restrict__ x, const float* __restrict__ g,
    const float* __restrict__ bt, ushort* __restrict__ y) {
  int lane = threadIdx.x & 63;
  int r = blockIdx.x * 4 + (threadIdx.x >> 6);
  const float4* xr = (const float4*)(x + (size_t)r * 512);
  float4 a = xr[lane];
  float4 c = xr[lane + 64];
  float s = a.x + a.y + a.z + a.w + c.x + c.y + c.z + c.w;
  float mean = wave_sum(s) * (1.f / 512.f);
  float d0 = a.x - mean, d1 = a.y - mean, d2 = a.z - mean, d3 = a.w - mean;
  float e0 = c.x - mean, e1 = c.y - mean, e2 = c.z - mean, e3 = c.w - mean;
  float vs = d0 * d0 + d1 * d1 + d2 * d2 + d3 * d3 +
             e0 * e0 + e1 * e1 + e2 * e2 + e3 * e3;
  float var = wave_sum(vs) * (1.f / 512.f);
  float rs = rsqrtf(var + 1e-5f);
  const float4* g4 = (const float4*)g;
  const float4* b4 = (const float4*)bt;
  float4 g0 = g4[lane], g1 = g4[lane + 64];
  float4 b0 = b4[lane], b1 = b4[lane + 64];
  ushort4 o0 = {f2b(d0 * rs * g0.x + b0.x), f2b(d1 * rs * g0.y + b0.y),
                f2b(d2 * rs * g0.z + b0.z), f2b(d3 * rs * g0.w + b0.w)};
  ushort4 o1 = {f2b(e0 * rs * g1.x + b1.x), f2b(e1 * rs * g1.y + b1.y),
                f2b(e2 * rs * g1.z + b1.z), f2b(e3 * rs * g1.w + b1.w)};
  ushort4* yr = (ushort4*)(y + (size_t)r * 512);
  yr[lane] = o0;
  yr[lane + 64] = o1;
}

// ---------------------------------------------------------------------------
// Weight prep: transpose+convert src[K][N] f32 -> dst[N][K] bf16, job table.
// ---------------------------------------------------------------------------
struct PJobs {
  const float* s[19];
  ushort* d[19];
};
__global__ __launch_bounds__(256) void k_wprep(PJobs j, int K, int N) {
  const float* src = j.s[blockIdx.z];
  ushort* dst = j.d[blockIdx.z];
  __shared__ float ld[32][33];
  int n0 = blockIdx.x * 32, k0 = blockIdx.y * 32;
  int c = threadIdx.x & 31, r0 = threadIdx.x >> 5;
#pragma unroll
  for (int i = 0; i < 4; i++)
    ld[r0 + i * 8][c] = src[(size_t)(k0 + r0 + i * 8) * N + n0 + c];
  __syncthreads();
#pragma unroll
  for (int i = 0; i < 4; i++)
    dst[(size_t)(n0 + r0 + i * 8) * K + k0 + c] = f2b(ld[c][r0 + i * 8]);
}

// rel [L][65][64] f32 -> [L][80][64] bf16 *8 (compensates Q prescale), pad 0
__global__ __launch_bounds__(256) void k_relprep(const float* __restrict__ rel,
                                                 ushort* __restrict__ relb) {
  int i = blockIdx.x * 256 + threadIdx.x;  // 0..5119
  int l = blockIdx.y;
  int r = i >> 6, d = i & 63;
  float v = (r < 65) ? rel[((size_t)l * 65 + r) * 64 + d] * 8.f : 0.f;
  relb[(size_t)l * 80 * 64 + i] = f2b(v);
}

// ---------------------------------------------------------------------------
// bf16 MFMA GEMM: double-buffered global_load_lds(16B) + source XOR swizzle,
// issue-next-before-compute (2-phase pipeline), XCD-chunked grid.
// MODE 0: bf16 out; 1: fp32 residual in-place; 2: gelu bf16;
// 3: residual + bf16 copy to C2.
// FUSEB 0: single bias; 1: QKV (3 biases + Q*0.125 + V^T-only write for V);
// 2: KV fused (2 biases).
// ---------------------------------------------------------------------------
template <int BM, int BN, int MODE, int FUSEB>
__global__ __launch_bounds__(256) void k_mg(
    const ushort* __restrict__ A, const ushort* __restrict__ Bt,
    const float* __restrict__ bias0, const float* __restrict__ bias1,
    const float* __restrict__ bias2, void* __restrict__ Cv,
    ushort* __restrict__ C2, int K, int ldc, int gx) {
  __shared__ __align__(16) ushort As[2][BM * 64];
  __shared__ __align__(16) ushort Bs[2][BN * 64];
  int nwg = gridDim.x;
  int id = blockIdx.x;
  int logical = (id & 7) * (nwg >> 3) + (id >> 3);
  int bx = logical % gx, by = logical / gx;
  int row0 = by * BM, col0 = bx * BN;
  int t = threadIdx.x, lane = t & 63, w = t >> 6;
  int rl15 = lane & 15, l16 = lane >> 4;
  constexpr int WR = (BM == 128 && BN == 128) ? 2 : BM / 32;
  constexpr int WC = 4 / WR;
  constexpr int MI = BM / (WR * 16);
  constexpr int NI = BN / (WC * 16);
  int wr = w % WR, wc = w / WR;
  int wrow = wr * MI * 16;
  int wcol = wc * NI * 16;
  f32x4 acc[MI][NI] = {};

  auto stage = [&](int buf, int kb) {
#pragma unroll
    for (int i = 0; i < BM / 32; i++) {
      int blk = w * (BM / 32) + i;
      int lb = blk * 1024 + lane * 16;
      int lg = swz128(lb);
      int r = lg >> 7, cb = (lg & 127) >> 1;
      __builtin_amdgcn_global_load_lds(
          (global_cvoid*)(A + (size_t)(row0 + r) * K + kb + cb),
          (lds_void*)((char*)As[buf] + blk * 1024), 16, 0, 0);
    }
#pragma unroll
    for (int i = 0; i < BN / 32; i++) {
      int blk = w * (BN / 32) + i;
      int lb = blk * 1024 + lane * 16;
      int lg = swz128(lb);
      int r = lg >> 7, cb = (lg & 127) >> 1;
      __builtin_amdgcn_global_load_lds(
          (global_cvoid*)(Bt + (size_t)(col0 + r) * K + kb + cb),
          (lds_void*)((char*)Bs[buf] + blk * 1024), 16, 0, 0);
    }
  };

  stage(0, 0);
  __syncthreads();
  int nkt = K >> 6;
  for (int kt = 0; kt < nkt; kt++) {
    int cur = kt & 1;
    if (kt + 1 < nkt) stage(cur ^ 1, (kt + 1) << 6);
#pragma unroll
    for (int ks = 0; ks < 2; ks++) {
      bf16x8 af[MI], bfr[NI];
#pragma unroll
      for (int mi = 0; mi < MI; mi++) {
        int row = wrow + mi * 16 + rl15;
        af[mi] =
            *(const bf16x8*)((char*)As[cur] + swz128(row * 128 + ks * 64 + l16 * 16));
      }
#pragma unroll
      for (int ni = 0; ni < NI; ni++) {
        int row = wcol + ni * 16 + rl15;
        bfr[ni] =
            *(const bf16x8*)((char*)Bs[cur] + swz128(row * 128 + ks * 64 + l16 * 16));
      }
#pragma unroll
      for (int mi = 0; mi < MI; mi++)
#pragma unroll
        for (int ni = 0; ni < NI; ni++)
          acc[mi][ni] = __builtin_amdgcn_mfma_f32_16x16x32_bf16(af[mi], bfr[ni],
                                                                acc[mi][ni], 0, 0, 0);
    }
    __syncthreads();
  }
#pragma unroll
  for (int mi = 0; mi < MI; mi++) {
#pragma unroll
    for (int ni = 0; ni < NI; ni++) {
      int col = col0 + wcol + ni * 16 + rl15;
      float bv;
      if (FUSEB == 1) {
        const float* bp = bias0;
        int c = col;
        if (c >= 1024) { bp = bias2; c -= 1024; }
        else if (c >= 512) { bp = bias1; c -= 512; }
        bv = bp[c];
      } else if (FUSEB == 2) {
        bv = (col < 512) ? bias0[col] : bias1[col - 512];
      } else {
        bv = bias0[col];
      }
#pragma unroll
      for (int r = 0; r < 4; r++) {
        int row = row0 + wrow + mi * 16 + l16 * 4 + r;
        float val = acc[mi][ni][r] + bv;
        if (FUSEB == 1 && col < 512) val *= 0.125f;  // fold 1/sqrt(HD) into Q
        if (MODE == 0) {
          ushort bval = f2b(val);
          if (FUSEB == 1 && col >= 1024) {
            // V: only the transposed copy is consumed (attn reads vT)
            int dg = col - 1024;
            int bh = (row >> 10) * 8 + (dg >> 6);
            C2[((size_t)bh * 64 + (dg & 63)) * 1024 + (row & 1023)] = bval;
          } else {
            ((ushort*)Cv)[(size_t)row * ldc + col] = bval;
          }
        } else if (MODE == 1) {
          float* Cp = (float*)Cv + (size_t)row * ldc + col;
          *Cp = *Cp + val;
        } else if (MODE == 2) {
          val = 0.5f * val * (1.f + erff(val * 0.70710678118654752f));
          ((ushort*)Cv)[(size_t)row * ldc + col] = f2b(val);
        } else {
          float* Cp = (float*)Cv + (size_t)row * ldc + col;
          float nv = *Cp + val;
          *Cp = nv;
          C2[(size_t)row * ldc + col] = f2b(nv);
        }
      }
    }
  }
}

// ---------------------------------------------------------------------------
// MFMA flash attention v4 (R6/R11-proven): double-buffered LDS K/V
// (issue-before-compute), swapped QK^T (lane owns one query row),
// defer-max, XCD-locality swizzle. grid 512, 256 threads = 4 waves.
// Q prescaled 1/8, rel prescaled 8.
// ---------------------------------------------------------------------------
__global__ __launch_bounds__(256) void k_attn3(
    const ushort* __restrict__ qkv, const ushort* __restrict__ vT,
    const ushort* __restrict__ relb, ushort* __restrict__ ao) {
  __shared__ __align__(16) ushort Ks[2][64 * 64];
  __shared__ __align__(16) ushort Vts[2][64 * 64];
  __shared__ ushort qrlb[4][16][66];
  __shared__ __align__(16) ushort Pl[4][16 * 72];
  int t = threadIdx.x, lane = t & 63, w = t >> 6;
  int bid = blockIdx.x;
  int p = bid & 31;
  int h = p & 7, b = p >> 3;
  int q0 = (bid >> 5) * 64;
  int qw = q0 + w * 16;
  int rl15 = lane & 15, l16 = lane >> 4;
  size_t baseq = ((size_t)b * 1024) * 1536 + h * 64;
  size_t basek = baseq + 512;
  const ushort* vTb = vT + ((size_t)(b * 8 + h)) * 64 * 1024;

  bf16x8 aq[2];
#pragma unroll
  for (int ks = 0; ks < 2; ks++)
    aq[ks] = *(const bf16x8*)(qkv + baseq + (size_t)(qw + rl15) * 1536 + ks * 32 + l16 * 8);

  // qrl[qrow][r] = Q'.rel'[r] (wave-private)
#pragma unroll
  for (int nb = 0; nb < 5; nb++) {
    f32x4 rc = {};
#pragma unroll
    for (int ks = 0; ks < 2; ks++) {
      bf16x8 rb =
          *(const bf16x8*)(relb + (size_t)(nb * 16 + rl15) * 64 + ks * 32 + l16 * 8);
      rc = __builtin_amdgcn_mfma_f32_16x16x32_bf16(aq[ks], rb, rc, 0, 0, 0);
    }
    int col = nb * 16 + rl15;
    if (col < 65) {
#pragma unroll
      for (int r = 0; r < 4; r++) qrlb[w][l16 * 4 + r][col] = f2b(rc[r]);
    }
  }

  auto stage = [&](int buf, int kb) {
#pragma unroll
    for (int i = 0; i < 2; i++) {
      int blk = w * 2 + i;
      int lb = blk * 1024 + lane * 16;
      int lg = swz128(lb);
      int r = lg >> 7, cb = (lg & 127) >> 1;
      __builtin_amdgcn_global_load_lds(
          (global_cvoid*)(qkv + basek + (size_t)(kb + r) * 1536 + cb),
          (lds_void*)((char*)Ks[buf] + blk * 1024), 16, 0, 0);
      __builtin_amdgcn_global_load_lds(
          (global_cvoid*)(vTb + (size_t)r * 1024 + kb + cb),
          (lds_void*)((char*)Vts[buf] + blk * 1024), 16, 0, 0);
    }
  };

  // online-softmax state: lane owns query rl15 (replicated over l16 groups)
  float m_own = -1e30f, l_own = 0.f;
  f32x4 oacc[4] = {};  // PV accum, rows = queries l16*4+r (C-layout)

  stage(0, 0);
  __syncthreads();

  for (int kt = 0; kt < 16; kt++) {
    int kb = kt << 6;
    int cur = kt & 1;
    if (kt < 15) stage(cur ^ 1, kb + 64);

    // S^T = K Q^T : col=rl15=query, row=l16*4+r(+16nb)=key
    f32x4 sacc[4] = {};
#pragma unroll
    for (int ks = 0; ks < 2; ks++) {
#pragma unroll
      for (int nb = 0; nb < 4; nb++) {
        bf16x8 kf = *(const bf16x8*)((char*)Ks[cur] +
                                     swz128((nb * 16 + rl15) * 128 + ks * 64 + l16 * 16));
        sacc[nb] = __builtin_amdgcn_mfma_f32_16x16x32_bf16(kf, aq[ks], sacc[nb], 0, 0, 0);
      }
    }

    // rel add: uniform fast path vs banded path (lane's query = rl15)
    float sv[4][4];
    bool hiU = (kb >= qw + 47);
    bool loU = (kb + 95 <= qw);
    if (hiU || loU) {
      float crow = b2f(qrlb[w][rl15][hiU ? 64 : 0]);
#pragma unroll
      for (int nb = 0; nb < 4; nb++)
#pragma unroll
        for (int r = 0; r < 4; r++) sv[nb][r] = sacc[nb][r] + crow;
    } else {
      int qg = qw + rl15;
#pragma unroll
      for (int nb = 0; nb < 4; nb++)
#pragma unroll
        for (int r = 0; r < 4; r++) {
          int delta = kb + nb * 16 + l16 * 4 + r - qg;
          delta = delta < -32 ? -32 : (delta > 32 ? 32 : delta);
          sv[nb][r] = sacc[nb][r] + b2f(qrlb[w][rl15][delta + 32]);
        }
    }

    // row max: 15 local fmax + 2 shfl (across l16 groups)
    float rowm = sv[0][0];
#pragma unroll
    for (int nb = 0; nb < 4; nb++)
#pragma unroll
      for (int r = 0; r < 4; r++) rowm = fmaxf(rowm, sv[nb][r]);
    rowm = fmaxf(rowm, __shfl_xor(rowm, 16, 64));
    rowm = fmaxf(rowm, __shfl_xor(rowm, 32, 64));

    if (__any(rowm > m_own + 8.f)) {  // defer-max THR=8
      float mn = fmaxf(m_own, rowm);
      float sc = __expf(m_own - mn);
      m_own = mn;
      l_own *= sc;
      float s0 = __shfl(sc, l16 * 4 + 0, 64);
      float s1 = __shfl(sc, l16 * 4 + 1, 64);
      float s2 = __shfl(sc, l16 * 4 + 2, 64);
      float s3 = __shfl(sc, l16 * 4 + 3, 64);
#pragma unroll
      for (int nb = 0; nb < 4; nb++) {
        oacc[nb][0] *= s0;
        oacc[nb][1] *= s1;
        oacc[nb][2] *= s2;
        oacc[nb][3] *= s3;
      }
    }

    float pv[4][4];
    float ls = 0.f;
#pragma unroll
    for (int nb = 0; nb < 4; nb++)
#pragma unroll
      for (int r = 0; r < 4; r++) {
        float e = __expf(sv[nb][r] - m_own);
        pv[nb][r] = e;
        ls += e;
      }
    ls += __shfl_xor(ls, 16, 64);
    ls += __shfl_xor(ls, 32, 64);
    l_own += ls;

    // P -> wave-private LDS as [query=rl15][key], paired u32 writes
#pragma unroll
    for (int nb = 0; nb < 4; nb++) {
      uint w0 = (uint)f2b(pv[nb][0]) | ((uint)f2b(pv[nb][1]) << 16);
      uint w1 = (uint)f2b(pv[nb][2]) | ((uint)f2b(pv[nb][3]) << 16);
      uint* dst = (uint*)&Pl[w][rl15 * 72 + nb * 16 + l16 * 4];
      dst[0] = w0;
      dst[1] = w1;
    }
    // PV: A = P (rows=queries), B = V^T frags
#pragma unroll
    for (int ks = 0; ks < 2; ks++) {
      bf16x8 pa = *(const bf16x8*)&Pl[w][rl15 * 72 + ks * 32 + l16 * 8];
#pragma unroll
      for (int nb = 0; nb < 4; nb++) {
        bf16x8 bv8 = *(const bf16x8*)((char*)Vts[cur] +
                                      swz128((nb * 16 + rl15) * 128 + ks * 64 + l16 * 16));
        oacc[nb] = __builtin_amdgcn_mfma_f32_16x16x32_bf16(pa, bv8, oacc[nb], 0, 0, 0);
      }
    }
    __syncthreads();
  }

  // final: redistribute l to PV-row ownership and write
  float linv[4];
#pragma unroll
  for (int r = 0; r < 4; r++) linv[r] = 1.f / __shfl(l_own, l16 * 4 + r, 64);
  size_t baseo = ((size_t)b * 1024) * 512 + h * 64;
#pragma unroll
  for (int nb = 0; nb < 4; nb++) {
    int d = nb * 16 + rl15;
#pragma unroll
    for (int r = 0; r < 4; r++) {
      int row = q0 + w * 16 + l16 * 4 + r;
      ao[baseo + (size_t)row * 512 + d] = f2b(oacc[nb][r] * linv[r]);
    }
  }
}

// ---------------------------------------------------------------------------
// Final global attention v2: computes last-row Q in-kernel (xn @ gWq),
// then streams the KV-only buffer [4096][1024] (k at 0, v at 512).
// ---------------------------------------------------------------------------
__global__ __launch_bounds__(256) void k_gattn2(
    const ushort* __restrict__ xn, const float* __restrict__ gWq,
    const float* __restrict__ gbq, const ushort* __restrict__ kv,
    float* __restrict__ ctxa) {
  int t = threadIdx.x;
  int h = blockIdx.x & 7, b = blockIdx.x >> 3;
  __shared__ float Qs[64];
  __shared__ float qp[4][64];
  __shared__ float sc[1024];
  __shared__ float red[4];
  __shared__ float op[4][64];
  {
    int d = t & 63, q = t >> 6;
    const ushort* xr = xn + (size_t)(b * 1024 + 1023) * 512;
    float acc = 0.f;
    for (int k = q * 128; k < q * 128 + 128; k++)
      acc += b2f(xr[k]) * gWq[(size_t)k * 512 + h * 64 + d];
    qp[q][d] = acc;
  }
  __syncthreads();
  if (t < 64)
    Qs[t] = (qp[0][t] + qp[1][t] + qp[2][t] + qp[3][t] + gbq[h * 64 + t]) * 0.125f;
  __syncthreads();
  float lm = -1e30f;
  float sv[4];
#pragma unroll
  for (int jj = 0; jj < 4; jj++) {
    int j = t + (jj << 8);
    const bf16x8* kp = (const bf16x8*)(kv + (size_t)(b * 1024 + j) * 1024 + h * 64);
    float s = 0.f;
#pragma unroll
    for (int c = 0; c < 8; c++) {
      bf16x8 v8 = kp[c];
#pragma unroll
      for (int e = 0; e < 8; e++) s += Qs[c * 8 + e] * b2f((ushort)v8[e]);
    }
    sv[jj] = s;
    lm = fmaxf(lm, s);
  }
  float bm = block_max(lm, red);
  float ls = 0.f;
#pragma unroll
  for (int jj = 0; jj < 4; jj++) {
    float e = __expf(sv[jj] - bm);
    sc[t + (jj << 8)] = e;
    ls += e;
  }
  float bs = block_sum(ls, red);
  int d = t & 63, qd = t >> 6;
  float acc = 0.f;
  for (int j = qd << 8; j < (qd << 8) + 256; j++)
    acc += sc[j] * b2f(kv[(size_t)(b * 1024 + j) * 1024 + 512 + h * 64 + d]);
  op[qd][d] = acc;
  __syncthreads();
  if (t < 64) {
    float r = (op[0][t] + op[1][t] + op[2][t] + op[3][t]) / bs;
    ctxa[b * 512 + h * 64 + t] = r;
  }
}

// ---------------------------------------------------------------------------
// 4-row GEMM (fp32) parallel: ctx = attnlast @ gWo + gbo.
// ---------------------------------------------------------------------------
__global__ __launch_bounds__(256) void k_rowgemm(
    const float* __restrict__ xrow, const float* __restrict__ W,
    const float* __restrict__ bias, float* __restrict__ y) {
  int b = blockIdx.x >> 4;
  int col0 = (blockIdx.x & 15) * 32;
  int t = threadIdx.x;
  int col = t & 31, kq = t >> 5;  // 8 k-groups of 64
  __shared__ float xs[512];
  __shared__ float part[8][32];
  if (t < 128) ((float4*)xs)[t] = ((const float4*)(xrow + b * 512))[t];
  __syncthreads();
  float acc = 0.f;
  const float* Wp = W + (size_t)(kq * 64) * 512 + col0 + col;
#pragma unroll 8
  for (int k = 0; k < 64; k++) acc += xs[kq * 64 + k] * Wp[(size_t)k * 512];
  part[kq][col] = acc;
  __syncthreads();
  if (t < 32) {
    float s = part[0][t] + part[1][t] + part[2][t] + part[3][t] +
              part[4][t] + part[5][t] + part[6][t] + part[7][t];
    y[b * 512 + col0 + t] = s + bias[col0 + t];
  }
}

// ---------------------------------------------------------------------------
// Head MLP (fp32), 512 threads: 2-way K-split on the D2=256 projection.
// ---------------------------------------------------------------------------
__global__ __launch_bounds__(512) void k_head(
    const float* __restrict__ ctx, const float* __restrict__ hW1,
    const float* __restrict__ hb1, const float* __restrict__ hg,
    const float* __restrict__ hbt, const float* __restrict__ hW2,
    const float* __restrict__ hb2, float* __restrict__ out) {
  int b = blockIdx.x / 3, nh = blockIdx.x % 3;
  int t = threadIdx.x;
  __shared__ float cs[512];
  __shared__ float part[2][256];
  __shared__ float red[8];
  if (t < 128) ((float4*)cs)[t] = ((const float4*)(ctx + b * 512))[t];
  __syncthreads();
  {
    int col = t & 255, kh = t >> 8;
    float acc = 0.f;
    const float* Wp = hW1 + ((size_t)nh * 512 + kh * 256) * 256 + col;
#pragma unroll 8
    for (int d = 0; d < 256; d++) acc += cs[kh * 256 + d] * Wp[(size_t)d * 256];
    part[kh][col] = acc;
  }
  __syncthreads();
  float y = 0.f;
  if (t < 256) y = part[0][t] + part[1][t] + hb1[nh * 256 + t];
  float v = wave_sum(t < 256 ? y : 0.f);
  if ((t & 63) == 0) red[t >> 6] = v;
  __syncthreads();
  float mean = (red[0] + red[1] + red[2] + red[3] + red[4] + red[5] + red[6] +
                red[7]) * (1.f / 256.f);
  float dv = (t < 256) ? (y - mean) : 0.f;
  float v2 = wave_sum(dv * dv);
  __syncthreads();
  if ((t & 63) == 0) red[t >> 6] = v2;
  __syncthreads();
  float var = (red[0] + red[1] + red[2] + red[3] + red[4] + red[5] + red[6] +
               red[7]) * (1.f / 256.f);
  float rs = rsqrtf(var + 1e-5f);
  float yn = 0.f;
  if (t < 256) {
    yn = dv * rs * hg[nh * 256 + t] + hbt[nh * 256 + t];
    yn = fmaxf(yn, 0.f) * hW2[nh * 256 + t];
  }
  float v3 = wave_sum(yn);
  __syncthreads();
  if ((t & 63) == 0) red[t >> 6] = v3;
  __syncthreads();
  if (t == 0) {
    float s = red[0] + red[1] + red[2] + red[3] + red[4] + red[5] + red[6] + red[7];
    out[b * 3 + nh] = s + hb2[nh];
  }
}

// ---------------------------------------------------------------------------
extern "C" void kernel_launch(void* const* d_in, const int* in_sizes, int n_in,
                              void* d_out, int out_size, void* d_ws, size_t ws_size,
                              hipStream_t stream) {
  const float* x = (const float*)d_in[0];
  const float* in_W = (const float*)d_in[1];
  const float* in_b = (const float*)d_in[2];
  const float* in_lng = (const float*)d_in[3];
  const float* in_lnb = (const float*)d_in[4];
  const float* ln1_g = (const float*)d_in[5];
  const float* ln1_b = (const float*)d_in[6];
  const float* Wq = (const float*)d_in[7];
  const float* bq = (const float*)d_in[8];
  const float* Wk = (const float*)d_in[9];
  const float* bk = (const float*)d_in[10];
  const float* Wv = (const float*)d_in[11];
  const float* bv = (const float*)d_in[12];
  const float* Wo = (const float*)d_in[13];
  const float* bo = (const float*)d_in[14];
  const float* rel = (const float*)d_in[15];
  const float* ln2_g = (const float*)d_in[16];
  const float* ln2_b = (const float*)d_in[17];
  const float* W1 = (const float*)d_in[18];
  const float* b1 = (const float*)d_in[19];
  const float* W2 = (const float*)d_in[20];
  const float* b2 = (const float*)d_in[21];
  const float* gWq = (const float*)d_in[22];
  const float* gbq = (const float*)d_in[23];
  const float* gWk = (const float*)d_in[24];
  const float* gbk = (const float*)d_in[25];
  const float* gWv = (const float*)d_in[26];
  const float* gbv = (const float*)d_in[27];
  const float* gWo = (const float*)d_in[28];
  const float* gbo = (const float*)d_in[29];
  const float* hW1 = (const float*)d_in[30];
  const float* hb1 = (const float*)d_in[31];
  const float* hlng = (const float*)d_in[32];
  const float* hlnb = (const float*)d_in[33];
  const float* hW2 = (const float*)d_in[34];
  const float* hb2 = (const float*)d_in[35];
  float* out = (float*)d_out;

  uint8_t* wsb = (uint8_t*)d_ws;
  const size_t MB = 1024 * 1024;
  float* h = (float*)(wsb + 0);              // 8 MB
  ushort* xn = (ushort*)(wsb + 8 * MB);      // 4 MB
  ushort* qkvb = (ushort*)(wsb + 12 * MB);   // 12 MB  [4096][1536]
  ushort* kvb = qkvb;                        // final KV [4096][1024] (reuse)
  ushort* aob = (ushort*)(wsb + 24 * MB);    // 4 MB
  ushort* ffb = (ushort*)(wsb + 28 * MB);    // 16 MB  [4096][2048]
  ushort* vTb = ffb;                         // 4 MB, time-shared with ffb
  ushort* wqkv = (ushort*)(wsb + 44 * MB);   // 4 x 1.5 MB
  ushort* wto = (ushort*)(wsb + 50 * MB);    // 4 x 0.5 MB
  ushort* wt1 = (ushort*)(wsb + 52 * MB);    // 4 x 2 MB
  ushort* wt2 = (ushort*)(wsb + 60 * MB);    // 4 x 2 MB
  ushort* gwkv = (ushort*)(wsb + 68 * MB);   // 1 MB (gWk,gWv transposed)
  ushort* relb = (ushort*)(wsb + 70 * MB);   // 40 KB
  float* attnlast = (float*)(wsb + 71 * MB);
  float* ctx = attnlast + 4096;

  const size_t W55 = 512 * 512;

  // ---- upfront weight prep ----
  {
    PJobs j{};
    for (int l = 0; l < 4; l++) {
      j.s[l * 4 + 0] = Wq + (size_t)l * W55;
      j.d[l * 4 + 0] = wqkv + (size_t)l * 1536 * 512;
      j.s[l * 4 + 1] = Wk + (size_t)l * W55;
      j.d[l * 4 + 1] = wqkv + (size_t)l * 1536 * 512 + 512 * 512;
      j.s[l * 4 + 2] = Wv + (size_t)l * W55;
      j.d[l * 4 + 2] = wqkv + (size_t)l * 1536 * 512 + 1024 * 512;
      j.s[l * 4 + 3] = Wo + (size_t)l * W55;
      j.d[l * 4 + 3] = wto + (size_t)l * W55;
    }
    j.s[16] = gWk; j.d[16] = gwkv;
    j.s[17] = gWv; j.d[17] = gwkv + 512 * 512;
    k_wprep<<<dim3(16, 16, 18), 256, 0, stream>>>(j, 512, 512);
  }
  {
    PJobs j{};
    for (int l = 0; l < 4; l++) {
      j.s[l] = W1 + (size_t)l * 512 * 2048;
      j.d[l] = wt1 + (size_t)l * 2048 * 512;
    }
    k_wprep<<<dim3(64, 16, 4), 256, 0, stream>>>(j, 512, 2048);
  }
  {
    PJobs j{};
    for (int l = 0; l < 4; l++) {
      j.s[l] = W2 + (size_t)l * 2048 * 512;
      j.d[l] = wt2 + (size_t)l * 512 * 2048;
    }
    k_wprep<<<dim3(16, 64, 4), 256, 0, stream>>>(j, 2048, 512);
  }
  k_relprep<<<dim3(20, 4), 256, 0, stream>>>(rel, relb);
  // input projection with fused layer-0 ln1 -> writes h AND xn
  k_inproj<<<1024, 256, 0, stream>>>(x, in_W, in_b, in_lng, in_lnb,
                                     ln1_g, ln1_b, h, xn);

  for (int l = 0; l < 4; l++) {
    size_t vo = (size_t)l * 512;
    if (l > 0) k_lnw<<<1024, 256, 0, stream>>>(h, ln1_g + vo, ln1_b + vo, xn);
    // fused QKV (V written only as V^T into vTb)
    k_mg<128, 64, 0, 1><<<768, 256, 0, stream>>>(xn, wqkv + (size_t)l * 1536 * 512,
                                                 bq + vo, bk + vo, bv + vo, qkvb,
                                                 vTb, 512, 1536, 24);
    k_attn3<<<512, 256, 0, stream>>>(qkvb, vTb, relb + (size_t)l * 80 * 64, aob);
    k_mg<64, 64, 1, 0><<<512, 256, 0, stream>>>(aob, wto + (size_t)l * W55, bo + vo,
                                                nullptr, nullptr, h, nullptr, 512, 512, 8);
    k_lnw<<<1024, 256, 0, stream>>>(h, ln2_g + vo, ln2_b + vo, xn);
    k_mg<128, 128, 2, 0><<<512, 256, 0, stream>>>(xn, wt1 + (size_t)l * 2048 * 512,
                                                  b1 + (size_t)l * 2048, nullptr, nullptr,
                                                  ffb, nullptr, 512, 2048, 16);
    if (l < 3)
      k_mg<64, 64, 1, 0><<<512, 256, 0, stream>>>(ffb, wt2 + (size_t)l * 512 * 2048,
                                                  b2 + vo, nullptr, nullptr, h, nullptr,
                                                  2048, 512, 8);
    else
      k_mg<64, 64, 3, 0><<<512, 256, 0, stream>>>(ffb, wt2 + (size_t)l * 512 * 2048,
                                                  b2 + vo, nullptr, nullptr, h, xn,
                                                  2048, 512, 8);
  }

  // final global attention: KV-only GEMM + in-kernel Q
  k_mg<128, 64, 0, 2><<<512, 256, 0, stream>>>(xn, gwkv, gbk, gbv, nullptr, kvb,
                                               nullptr, 512, 1024, 16);
  k_gattn2<<<32, 256, 0, stream>>>(xn, gWq, gbq, kvb, attnlast);
  k_rowgemm<<<64, 256, 0, stream>>>(attnlast, gWo, gbo, ctx);
  k_head<<<12, 512, 0, stream>>>(ctx, hW1, hb1, hlng, hlnb, hW2, hb2, out);
}

// Round 14
// 510.433 us; speedup vs baseline: 1.1085x; 1.0037x over previous
//
#include <hip/hip_runtime.h>
#include <math.h>

#define DEV __device__ __forceinline__

// B=4, S=1024, F=20, D=512, H=8, L=4, FF=2048, M=32, NH=3, D2=256, O=1, HD=64
constexpr int BSD = 4 * 1024 * 512;  // B*S*D

typedef __attribute__((ext_vector_type(8))) short bf16x8;
typedef __attribute__((ext_vector_type(4))) float f32x4;

typedef __attribute__((address_space(1))) const void global_cvoid;
typedef __attribute__((address_space(3))) void lds_void;

DEV ushort f2b(float f) {
  union { float f; uint u; } x{f};
  uint r = x.u + 0x7fff + ((x.u >> 16) & 1);
  return (ushort)(r >> 16);
}
DEV float b2f(ushort u) {
  union { uint u; float f; } x{(uint)u << 16};
  return x.f;
}
DEV int swz128(int b) { return b ^ (((b >> 7) & 7) << 4); }

DEV float wave_sum(float v) {
#pragma unroll
  for (int m = 32; m >= 1; m >>= 1) v += __shfl_xor(v, m, 64);
  return v;
}
DEV float wave_max(float v) {
#pragma unroll
  for (int m = 32; m >= 1; m >>= 1) v = fmaxf(v, __shfl_xor(v, m, 64));
  return v;
}
DEV float block_sum(float v, float* sm) {
  v = wave_sum(v);
  __syncthreads();
  if ((threadIdx.x & 63) == 0) sm[threadIdx.x >> 6] = v;
  __syncthreads();
  return sm[0] + sm[1] + sm[2] + sm[3];
}
DEV float block_max(float v, float* sm) {
  v = wave_max(v);
  __syncthreads();
  if ((threadIdx.x & 63) == 0) sm[threadIdx.x >> 6] = v;
  __syncthreads();
  return fmaxf(fmaxf(sm[0], sm[1]), fmaxf(sm[2], sm[3]));
}

// ---------------------------------------------------------------------------
// Input projection, wave-per-row: h = LN(x @ in_W + in_b)*g + b + posenc.
// ALSO fuses layer-0 ln1: xn = bf16(LN(h)*l1g + l1b).
// ---------------------------------------------------------------------------
__global__ __launch_bounds__(256) void k_inproj(
    const float* __restrict__ x, const float* __restrict__ W,
    const float* __restrict__ bias, const float* __restrict__ g,
    const float* __restrict__ bt, const float* __restrict__ l1g,
    const float* __restrict__ l1b, float* __restrict__ h,
    ushort* __restrict__ xn) {
  int lane = threadIdx.x & 63;
  int r = blockIdx.x * 4 + (threadIdx.x >> 6);
  int s = r & 1023;
  float xr[20];
#pragma unroll
  for (int f = 0; f < 20; f++) xr[f] = x[r * 20 + f];  // wave-uniform
  float o[8];
#pragma unroll
  for (int j = 0; j < 8; j++) {
    int c = lane + 64 * j;
    float acc = bias[c];
#pragma unroll
    for (int f = 0; f < 20; f++) acc += xr[f] * W[f * 512 + c];
    o[j] = acc;
  }
  float ssum = 0.f;
#pragma unroll
  for (int j = 0; j < 8; j++) ssum += o[j];
  float mean = wave_sum(ssum) * (1.f / 512.f);
  float vs = 0.f;
#pragma unroll
  for (int j = 0; j < 8; j++) {
    o[j] -= mean;
    vs += o[j] * o[j];
  }
  float var = wave_sum(vs) * (1.f / 512.f);
  float rs = rsqrtf(var + 1e-5f);
  const float c1 = -9.210340371976184f / 512.f;
#pragma unroll
  for (int j = 0; j < 8; j++) {
    int c = lane + 64 * j;
    float n = o[j] * rs * g[c] + bt[c];
    float div = __expf((float)(c & ~1) * c1);
    float arg = (float)s * div;
    n += (c & 1) ? __cosf(arg) : __sinf(arg);
    h[(size_t)r * 512 + c] = n;
    o[j] = n;  // keep row for fused ln1
  }
  float s2 = 0.f;
#pragma unroll
  for (int j = 0; j < 8; j++) s2 += o[j];
  float mean2 = wave_sum(s2) * (1.f / 512.f);
  float vs2 = 0.f;
#pragma unroll
  for (int j = 0; j < 8; j++) {
    o[j] -= mean2;
    vs2 += o[j] * o[j];
  }
  float var2 = wave_sum(vs2) * (1.f / 512.f);
  float rs2 = rsqrtf(var2 + 1e-5f);
#pragma unroll
  for (int j = 0; j < 8; j++) {
    int c = lane + 64 * j;
    xn[(size_t)r * 512 + c] = f2b(o[j] * rs2 * l1g[c] + l1b[c]);
  }
}

// ---------------------------------------------------------------------------
// LayerNorm fp32 -> bf16, one wave per row (shfl-only), 4 rows/block.
// ---------------------------------------------------------------------------
__global__ __launch_bounds__(256) void k_lnw(
    const float* __restrict__ x, const float* __restrict__ g,
    const float* __restrict__ bt, ushort* __restrict__ y) {
  int lane = threadIdx.x & 63;
  int r = blockIdx.x * 4 + (threadIdx.x >> 6);
  const float4* xr = (const float4*)(x + (size_t)r * 512);
  float4 a = xr[lane];
  float4 c = xr[lane + 64];
  float s = a.x + a.y + a.z + a.w + c.x + c.y + c.z + c.w;
  float mean = wave_sum(s) * (1.f / 512.f);
  float d0 = a.x - mean, d1 = a.y - mean, d2 = a.z - mean, d3 = a.w - mean;
  float e0 = c.x - mean, e1 = c.y - mean, e2 = c.z - mean, e3 = c.w - mean;
  float vs = d0 * d0 + d1 * d1 + d2 * d2 + d3 * d3 +
             e0 * e0 + e1 * e1 + e2 * e2 + e3 * e3;
  float var = wave_sum(vs) * (1.f / 512.f);
  float rs = rsqrtf(var + 1e-5f);
  const float4* g4 = (const float4*)g;
  const float4* b4 = (const float4*)bt;
  float4 g0 = g4[lane], g1 = g4[lane + 64];
  float4 b0 = b4[lane], b1 = b4[lane + 64];
  ushort4 o0 = {f2b(d0 * rs * g0.x + b0.x), f2b(d1 * rs * g0.y + b0.y),
                f2b(d2 * rs * g0.z + b0.z), f2b(d3 * rs * g0.w + b0.w)};
  ushort4 o1 = {f2b(e0 * rs * g1.x + b1.x), f2b(e1 * rs * g1.y + b1.y),
                f2b(e2 * rs * g1.z + b1.z), f2b(e3 * rs * g1.w + b1.w)};
  ushort4* yr = (ushort4*)(y + (size_t)r * 512);
  yr[lane] = o0;
  yr[lane + 64] = o1;
}

// ---------------------------------------------------------------------------
// Weight prep: transpose+convert src[K][N] f32 -> dst[N][K] bf16, job table.
// ---------------------------------------------------------------------------
struct PJobs {
  const float* s[19];
  ushort* d[19];
};
__global__ __launch_bounds__(256) void k_wprep(PJobs j, int K, int N) {
  const float* src = j.s[blockIdx.z];
  ushort* dst = j.d[blockIdx.z];
  __shared__ float ld[32][33];
  int n0 = blockIdx.x * 32, k0 = blockIdx.y * 32;
  int c = threadIdx.x & 31, r0 = threadIdx.x >> 5;
#pragma unroll
  for (int i = 0; i < 4; i++)
    ld[r0 + i * 8][c] = src[(size_t)(k0 + r0 + i * 8) * N + n0 + c];
  __syncthreads();
#pragma unroll
  for (int i = 0; i < 4; i++)
    dst[(size_t)(n0 + r0 + i * 8) * K + k0 + c] = f2b(ld[c][r0 + i * 8]);
}

// rel [L][65][64] f32 -> [L][80][64] bf16 *8 (compensates Q prescale), pad 0
__global__ __launch_bounds__(256) void k_relprep(const float* __restrict__ rel,
                                                 ushort* __restrict__ relb) {
  int i = blockIdx.x * 256 + threadIdx.x;  // 0..5119
  int l = blockIdx.y;
  int r = i >> 6, d = i & 63;
  float v = (r < 65) ? rel[((size_t)l * 65 + r) * 64 + d] * 8.f : 0.f;
  relb[(size_t)l * 80 * 64 + i] = f2b(v);
}

// ---------------------------------------------------------------------------
// bf16 MFMA GEMM: double-buffered global_load_lds(16B) + source XOR swizzle,
// issue-next-before-compute (2-phase pipeline), XCD-chunked grid.
// MODE 0: bf16 out; 1: fp32 residual in-place; 2: gelu bf16;
// 3: residual + bf16 copy to C2.
// FUSEB 0: single bias; 1: QKV (3 biases + Q*0.125 + V^T-only write for V);
// 2: KV fused (2 biases).
// ---------------------------------------------------------------------------
template <int BM, int BN, int MODE, int FUSEB>
__global__ __launch_bounds__(256) void k_mg(
    const ushort* __restrict__ A, const ushort* __restrict__ Bt,
    const float* __restrict__ bias0, const float* __restrict__ bias1,
    const float* __restrict__ bias2, void* __restrict__ Cv,
    ushort* __restrict__ C2, int K, int ldc, int gx) {
  __shared__ __align__(16) ushort As[2][BM * 64];
  __shared__ __align__(16) ushort Bs[2][BN * 64];
  int nwg = gridDim.x;
  int id = blockIdx.x;
  int logical = (id & 7) * (nwg >> 3) + (id >> 3);
  int bx = logical % gx, by = logical / gx;
  int row0 = by * BM, col0 = bx * BN;
  int t = threadIdx.x, lane = t & 63, w = t >> 6;
  int rl15 = lane & 15, l16 = lane >> 4;
  constexpr int WR = (BM == 128 && BN == 128) ? 2 : BM / 32;
  constexpr int WC = 4 / WR;
  constexpr int MI = BM / (WR * 16);
  constexpr int NI = BN / (WC * 16);
  int wr = w % WR, wc = w / WR;
  int wrow = wr * MI * 16;
  int wcol = wc * NI * 16;
  f32x4 acc[MI][NI] = {};

  auto stage = [&](int buf, int kb) {
#pragma unroll
    for (int i = 0; i < BM / 32; i++) {
      int blk = w * (BM / 32) + i;
      int lb = blk * 1024 + lane * 16;
      int lg = swz128(lb);
      int r = lg >> 7, cb = (lg & 127) >> 1;
      __builtin_amdgcn_global_load_lds(
          (global_cvoid*)(A + (size_t)(row0 + r) * K + kb + cb),
          (lds_void*)((char*)As[buf] + blk * 1024), 16, 0, 0);
    }
#pragma unroll
    for (int i = 0; i < BN / 32; i++) {
      int blk = w * (BN / 32) + i;
      int lb = blk * 1024 + lane * 16;
      int lg = swz128(lb);
      int r = lg >> 7, cb = (lg & 127) >> 1;
      __builtin_amdgcn_global_load_lds(
          (global_cvoid*)(Bt + (size_t)(col0 + r) * K + kb + cb),
          (lds_void*)((char*)Bs[buf] + blk * 1024), 16, 0, 0);
    }
  };

  stage(0, 0);
  __syncthreads();
  int nkt = K >> 6;
  for (int kt = 0; kt < nkt; kt++) {
    int cur = kt & 1;
    if (kt + 1 < nkt) stage(cur ^ 1, (kt + 1) << 6);
#pragma unroll
    for (int ks = 0; ks < 2; ks++) {
      bf16x8 af[MI], bfr[NI];
#pragma unroll
      for (int mi = 0; mi < MI; mi++) {
        int row = wrow + mi * 16 + rl15;
        af[mi] =
            *(const bf16x8*)((char*)As[cur] + swz128(row * 128 + ks * 64 + l16 * 16));
      }
#pragma unroll
      for (int ni = 0; ni < NI; ni++) {
        int row = wcol + ni * 16 + rl15;
        bfr[ni] =
            *(const bf16x8*)((char*)Bs[cur] + swz128(row * 128 + ks * 64 + l16 * 16));
      }
#pragma unroll
      for (int mi = 0; mi < MI; mi++)
#pragma unroll
        for (int ni = 0; ni < NI; ni++)
          acc[mi][ni] = __builtin_amdgcn_mfma_f32_16x16x32_bf16(af[mi], bfr[ni],
                                                                acc[mi][ni], 0, 0, 0);
    }
    __syncthreads();
  }
#pragma unroll
  for (int mi = 0; mi < MI; mi++) {
#pragma unroll
    for (int ni = 0; ni < NI; ni++) {
      int col = col0 + wcol + ni * 16 + rl15;
      float bv;
      if (FUSEB == 1) {
        const float* bp = bias0;
        int c = col;
        if (c >= 1024) { bp = bias2; c -= 1024; }
        else if (c >= 512) { bp = bias1; c -= 512; }
        bv = bp[c];
      } else if (FUSEB == 2) {
        bv = (col < 512) ? bias0[col] : bias1[col - 512];
      } else {
        bv = bias0[col];
      }
#pragma unroll
      for (int r = 0; r < 4; r++) {
        int row = row0 + wrow + mi * 16 + l16 * 4 + r;
        float val = acc[mi][ni][r] + bv;
        if (FUSEB == 1 && col < 512) val *= 0.125f;  // fold 1/sqrt(HD) into Q
        if (MODE == 0) {
          ushort bval = f2b(val);
          if (FUSEB == 1 && col >= 1024) {
            // V: only the transposed copy is consumed (attn reads vT)
            int dg = col - 1024;
            int bh = (row >> 10) * 8 + (dg >> 6);
            C2[((size_t)bh * 64 + (dg & 63)) * 1024 + (row & 1023)] = bval;
          } else {
            ((ushort*)Cv)[(size_t)row * ldc + col] = bval;
          }
        } else if (MODE == 1) {
          float* Cp = (float*)Cv + (size_t)row * ldc + col;
          *Cp = *Cp + val;
        } else if (MODE == 2) {
          val = 0.5f * val * (1.f + erff(val * 0.70710678118654752f));
          ((ushort*)Cv)[(size_t)row * ldc + col] = f2b(val);
        } else {
          float* Cp = (float*)Cv + (size_t)row * ldc + col;
          float nv = *Cp + val;
          *Cp = nv;
          C2[(size_t)row * ldc + col] = f2b(nv);
        }
      }
    }
  }
}

// ---------------------------------------------------------------------------
// MFMA flash attention v4b: R13-proven structure + tree-shaped softmax
// reductions (depth 4 instead of 16) + s_setprio around MFMA clusters (T5).
// grid 512, 256 threads = 4 waves. Q prescaled 1/8, rel prescaled 8.
// ---------------------------------------------------------------------------
__global__ __launch_bounds__(256) void k_attn3(
    const ushort* __restrict__ qkv, const ushort* __restrict__ vT,
    const ushort* __restrict__ relb, ushort* __restrict__ ao) {
  __shared__ __align__(16) ushort Ks[2][64 * 64];
  __shared__ __align__(16) ushort Vts[2][64 * 64];
  __shared__ ushort qrlb[4][16][66];
  __shared__ __align__(16) ushort Pl[4][16 * 72];
  int t = threadIdx.x, lane = t & 63, w = t >> 6;
  int bid = blockIdx.x;
  int p = bid & 31;
  int h = p & 7, b = p >> 3;
  int q0 = (bid >> 5) * 64;
  int qw = q0 + w * 16;
  int rl15 = lane & 15, l16 = lane >> 4;
  size_t baseq = ((size_t)b * 1024) * 1536 + h * 64;
  size_t basek = baseq + 512;
  const ushort* vTb = vT + ((size_t)(b * 8 + h)) * 64 * 1024;

  bf16x8 aq[2];
#pragma unroll
  for (int ks = 0; ks < 2; ks++)
    aq[ks] = *(const bf16x8*)(qkv + baseq + (size_t)(qw + rl15) * 1536 + ks * 32 + l16 * 8);

  // qrl[qrow][r] = Q'.rel'[r] (wave-private)
#pragma unroll
  for (int nb = 0; nb < 5; nb++) {
    f32x4 rc = {};
#pragma unroll
    for (int ks = 0; ks < 2; ks++) {
      bf16x8 rb =
          *(const bf16x8*)(relb + (size_t)(nb * 16 + rl15) * 64 + ks * 32 + l16 * 8);
      rc = __builtin_amdgcn_mfma_f32_16x16x32_bf16(aq[ks], rb, rc, 0, 0, 0);
    }
    int col = nb * 16 + rl15;
    if (col < 65) {
#pragma unroll
      for (int r = 0; r < 4; r++) qrlb[w][l16 * 4 + r][col] = f2b(rc[r]);
    }
  }

  auto stage = [&](int buf, int kb) {
#pragma unroll
    for (int i = 0; i < 2; i++) {
      int blk = w * 2 + i;
      int lb = blk * 1024 + lane * 16;
      int lg = swz128(lb);
      int r = lg >> 7, cb = (lg & 127) >> 1;
      __builtin_amdgcn_global_load_lds(
          (global_cvoid*)(qkv + basek + (size_t)(kb + r) * 1536 + cb),
          (lds_void*)((char*)Ks[buf] + blk * 1024), 16, 0, 0);
      __builtin_amdgcn_global_load_lds(
          (global_cvoid*)(vTb + (size_t)r * 1024 + kb + cb),
          (lds_void*)((char*)Vts[buf] + blk * 1024), 16, 0, 0);
    }
  };

  // online-softmax state: lane owns query rl15 (replicated over l16 groups)
  float m_own = -1e30f, l_own = 0.f;
  f32x4 oacc[4] = {};  // PV accum, rows = queries l16*4+r (C-layout)

  stage(0, 0);
  __syncthreads();

  for (int kt = 0; kt < 16; kt++) {
    int kb = kt << 6;
    int cur = kt & 1;
    if (kt < 15) stage(cur ^ 1, kb + 64);

    // S^T = K Q^T : col=rl15=query, row=l16*4+r(+16nb)=key
    f32x4 sacc[4] = {};
    __builtin_amdgcn_s_setprio(1);
#pragma unroll
    for (int ks = 0; ks < 2; ks++) {
#pragma unroll
      for (int nb = 0; nb < 4; nb++) {
        bf16x8 kf = *(const bf16x8*)((char*)Ks[cur] +
                                     swz128((nb * 16 + rl15) * 128 + ks * 64 + l16 * 16));
        sacc[nb] = __builtin_amdgcn_mfma_f32_16x16x32_bf16(kf, aq[ks], sacc[nb], 0, 0, 0);
      }
    }
    __builtin_amdgcn_s_setprio(0);

    // rel add: uniform fast path vs banded path (lane's query = rl15)
    float sv[4][4];
    bool hiU = (kb >= qw + 47);
    bool loU = (kb + 95 <= qw);
    if (hiU || loU) {
      float crow = b2f(qrlb[w][rl15][hiU ? 64 : 0]);
#pragma unroll
      for (int nb = 0; nb < 4; nb++)
#pragma unroll
        for (int r = 0; r < 4; r++) sv[nb][r] = sacc[nb][r] + crow;
    } else {
      int qg = qw + rl15;
#pragma unroll
      for (int nb = 0; nb < 4; nb++)
#pragma unroll
        for (int r = 0; r < 4; r++) {
          int delta = kb + nb * 16 + l16 * 4 + r - qg;
          delta = delta < -32 ? -32 : (delta > 32 ? 32 : delta);
          sv[nb][r] = sacc[nb][r] + b2f(qrlb[w][rl15][delta + 32]);
        }
    }

    // row max: pairwise tree (depth 4) + 2 shfl (across l16 groups)
    float rm[4];
#pragma unroll
    for (int nb = 0; nb < 4; nb++)
      rm[nb] = fmaxf(fmaxf(sv[nb][0], sv[nb][1]), fmaxf(sv[nb][2], sv[nb][3]));
    float rowm = fmaxf(fmaxf(rm[0], rm[1]), fmaxf(rm[2], rm[3]));
    rowm = fmaxf(rowm, __shfl_xor(rowm, 16, 64));
    rowm = fmaxf(rowm, __shfl_xor(rowm, 32, 64));

    if (__any(rowm > m_own + 8.f)) {  // defer-max THR=8
      float mn = fmaxf(m_own, rowm);
      float sc = __expf(m_own - mn);
      m_own = mn;
      l_own *= sc;
      float s0 = __shfl(sc, l16 * 4 + 0, 64);
      float s1 = __shfl(sc, l16 * 4 + 1, 64);
      float s2 = __shfl(sc, l16 * 4 + 2, 64);
      float s3 = __shfl(sc, l16 * 4 + 3, 64);
#pragma unroll
      for (int nb = 0; nb < 4; nb++) {
        oacc[nb][0] *= s0;
        oacc[nb][1] *= s1;
        oacc[nb][2] *= s2;
        oacc[nb][3] *= s3;
      }
    }

    // exp + pairwise-tree row sum (depth 4) + 2 shfl
    float pv[4][4];
    float se[4];
#pragma unroll
    for (int nb = 0; nb < 4; nb++) {
      float e0 = __expf(sv[nb][0] - m_own);
      float e1 = __expf(sv[nb][1] - m_own);
      float e2 = __expf(sv[nb][2] - m_own);
      float e3 = __expf(sv[nb][3] - m_own);
      pv[nb][0] = e0; pv[nb][1] = e1; pv[nb][2] = e2; pv[nb][3] = e3;
      se[nb] = (e0 + e1) + (e2 + e3);
    }
    float ls = (se[0] + se[1]) + (se[2] + se[3]);
    ls += __shfl_xor(ls, 16, 64);
    ls += __shfl_xor(ls, 32, 64);
    l_own += ls;

    // P -> wave-private LDS as [query=rl15][key], paired u32 writes
#pragma unroll
    for (int nb = 0; nb < 4; nb++) {
      uint w0 = (uint)f2b(pv[nb][0]) | ((uint)f2b(pv[nb][1]) << 16);
      uint w1 = (uint)f2b(pv[nb][2]) | ((uint)f2b(pv[nb][3]) << 16);
      uint* dst = (uint*)&Pl[w][rl15 * 72 + nb * 16 + l16 * 4];
      dst[0] = w0;
      dst[1] = w1;
    }
    // PV: A = P (rows=queries), B = V^T frags
    __builtin_amdgcn_s_setprio(1);
#pragma unroll
    for (int ks = 0; ks < 2; ks++) {
      bf16x8 pa = *(const bf16x8*)&Pl[w][rl15 * 72 + ks * 32 + l16 * 8];
#pragma unroll
      for (int nb = 0; nb < 4; nb++) {
        bf16x8 bv8 = *(const bf16x8*)((char*)Vts[cur] +
                                      swz128((nb * 16 + rl15) * 128 + ks * 64 + l16 * 16));
        oacc[nb] = __builtin_amdgcn_mfma_f32_16x16x32_bf16(pa, bv8, oacc[nb], 0, 0, 0);
      }
    }
    __builtin_amdgcn_s_setprio(0);
    __syncthreads();
  }

  // final: redistribute l to PV-row ownership and write
  float linv[4];
#pragma unroll
  for (int r = 0; r < 4; r++) linv[r] = 1.f / __shfl(l_own, l16 * 4 + r, 64);
  size_t baseo = ((size_t)b * 1024) * 512 + h * 64;
#pragma unroll
  for (int nb = 0; nb < 4; nb++) {
    int d = nb * 16 + rl15;
#pragma unroll
    for (int r = 0; r < 4; r++) {
      int row = q0 + w * 16 + l16 * 4 + r;
      ao[baseo + (size_t)row * 512 + d] = f2b(oacc[nb][r] * linv[r]);
    }
  }
}

// ---------------------------------------------------------------------------
// Final global attention v2: computes last-row Q in-kernel (xn @ gWq),
// then streams the KV-only buffer [4096][1024] (k at 0, v at 512).
// ---------------------------------------------------------------------------
__global__ __launch_bounds__(256) void k_gattn2(
    const ushort* __restrict__ xn, const float* __restrict__ gWq,
    const float* __restrict__ gbq, const ushort* __restrict__ kv,
    float* __restrict__ ctxa) {
  int t = threadIdx.x;
  int h = blockIdx.x & 7, b = blockIdx.x >> 3;
  __shared__ float Qs[64];
  __shared__ float qp[4][64];
  __shared__ float sc[1024];
  __shared__ float red[4];
  __shared__ float op[4][64];
  {
    int d = t & 63, q = t >> 6;
    const ushort* xr = xn + (size_t)(b * 1024 + 1023) * 512;
    float acc = 0.f;
    for (int k = q * 128; k < q * 128 + 128; k++)
      acc += b2f(xr[k]) * gWq[(size_t)k * 512 + h * 64 + d];
    qp[q][d] = acc;
  }
  __syncthreads();
  if (t < 64)
    Qs[t] = (qp[0][t] + qp[1][t] + qp[2][t] + qp[3][t] + gbq[h * 64 + t]) * 0.125f;
  __syncthreads();
  float lm = -1e30f;
  float sv[4];
#pragma unroll
  for (int jj = 0; jj < 4; jj++) {
    int j = t + (jj << 8);
    const bf16x8* kp = (const bf16x8*)(kv + (size_t)(b * 1024 + j) * 1024 + h * 64);
    float s = 0.f;
#pragma unroll
    for (int c = 0; c < 8; c++) {
      bf16x8 v8 = kp[c];
#pragma unroll
      for (int e = 0; e < 8; e++) s += Qs[c * 8 + e] * b2f((ushort)v8[e]);
    }
    sv[jj] = s;
    lm = fmaxf(lm, s);
  }
  float bm = block_max(lm, red);
  float ls = 0.f;
#pragma unroll
  for (int jj = 0; jj < 4; jj++) {
    float e = __expf(sv[jj] - bm);
    sc[t + (jj << 8)] = e;
    ls += e;
  }
  float bs = block_sum(ls, red);
  int d = t & 63, qd = t >> 6;
  float acc = 0.f;
  for (int j = qd << 8; j < (qd << 8) + 256; j++)
    acc += sc[j] * b2f(kv[(size_t)(b * 1024 + j) * 1024 + 512 + h * 64 + d]);
  op[qd][d] = acc;
  __syncthreads();
  if (t < 64) {
    float r = (op[0][t] + op[1][t] + op[2][t] + op[3][t]) / bs;
    ctxa[b * 512 + h * 64 + t] = r;
  }
}

// ---------------------------------------------------------------------------
// 4-row GEMM (fp32) parallel: ctx = attnlast @ gWo + gbo.
// ---------------------------------------------------------------------------
__global__ __launch_bounds__(256) void k_rowgemm(
    const float* __restrict__ xrow, const float* __restrict__ W,
    const float* __restrict__ bias, float* __restrict__ y) {
  int b = blockIdx.x >> 4;
  int col0 = (blockIdx.x & 15) * 32;
  int t = threadIdx.x;
  int col = t & 31, kq = t >> 5;  // 8 k-groups of 64
  __shared__ float xs[512];
  __shared__ float part[8][32];
  if (t < 128) ((float4*)xs)[t] = ((const float4*)(xrow + b * 512))[t];
  __syncthreads();
  float acc = 0.f;
  const float* Wp = W + (size_t)(kq * 64) * 512 + col0 + col;
#pragma unroll 8
  for (int k = 0; k < 64; k++) acc += xs[kq * 64 + k] * Wp[(size_t)k * 512];
  part[kq][col] = acc;
  __syncthreads();
  if (t < 32) {
    float s = part[0][t] + part[1][t] + part[2][t] + part[3][t] +
              part[4][t] + part[5][t] + part[6][t] + part[7][t];
    y[b * 512 + col0 + t] = s + bias[col0 + t];
  }
}

// ---------------------------------------------------------------------------
// Head MLP (fp32), 512 threads: 2-way K-split on the D2=256 projection.
// ---------------------------------------------------------------------------
__global__ __launch_bounds__(512) void k_head(
    const float* __restrict__ ctx, const float* __restrict__ hW1,
    const float* __restrict__ hb1, const float* __restrict__ hg,
    const float* __restrict__ hbt, const float* __restrict__ hW2,
    const float* __restrict__ hb2, float* __restrict__ out) {
  int b = blockIdx.x / 3, nh = blockIdx.x % 3;
  int t = threadIdx.x;
  __shared__ float cs[512];
  __shared__ float part[2][256];
  __shared__ float red[8];
  if (t < 128) ((float4*)cs)[t] = ((const float4*)(ctx + b * 512))[t];
  __syncthreads();
  {
    int col = t & 255, kh = t >> 8;
    float acc = 0.f;
    const float* Wp = hW1 + ((size_t)nh * 512 + kh * 256) * 256 + col;
#pragma unroll 8
    for (int d = 0; d < 256; d++) acc += cs[kh * 256 + d] * Wp[(size_t)d * 256];
    part[kh][col] = acc;
  }
  __syncthreads();
  float y = 0.f;
  if (t < 256) y = part[0][t] + part[1][t] + hb1[nh * 256 + t];
  float v = wave_sum(t < 256 ? y : 0.f);
  if ((t & 63) == 0) red[t >> 6] = v;
  __syncthreads();
  float mean = (red[0] + red[1] + red[2] + red[3] + red[4] + red[5] + red[6] +
                red[7]) * (1.f / 256.f);
  float dv = (t < 256) ? (y - mean) : 0.f;
  float v2 = wave_sum(dv * dv);
  __syncthreads();
  if ((t & 63) == 0) red[t >> 6] = v2;
  __syncthreads();
  float var = (red[0] + red[1] + red[2] + red[3] + red[4] + red[5] + red[6] +
               red[7]) * (1.f / 256.f);
  float rs = rsqrtf(var + 1e-5f);
  float yn = 0.f;
  if (t < 256) {
    yn = dv * rs * hg[nh * 256 + t] + hbt[nh * 256 + t];
    yn = fmaxf(yn, 0.f) * hW2[nh * 256 + t];
  }
  float v3 = wave_sum(yn);
  __syncthreads();
  if ((t & 63) == 0) red[t >> 6] = v3;
  __syncthreads();
  if (t == 0) {
    float s = red[0] + red[1] + red[2] + red[3] + red[4] + red[5] + red[6] + red[7];
    out[b * 3 + nh] = s + hb2[nh];
  }
}

// ---------------------------------------------------------------------------
extern "C" void kernel_launch(void* const* d_in, const int* in_sizes, int n_in,
                              void* d_out, int out_size, void* d_ws, size_t ws_size,
                              hipStream_t stream) {
  const float* x = (const float*)d_in[0];
  const float* in_W = (const float*)d_in[1];
  const float* in_b = (const float*)d_in[2];
  const float* in_lng = (const float*)d_in[3];
  const float* in_lnb = (const float*)d_in[4];
  const float* ln1_g = (const float*)d_in[5];
  const float* ln1_b = (const float*)d_in[6];
  const float* Wq = (const float*)d_in[7];
  const float* bq = (const float*)d_in[8];
  const float* Wk = (const float*)d_in[9];
  const float* bk = (const float*)d_in[10];
  const float* Wv = (const float*)d_in[11];
  const float* bv = (const float*)d_in[12];
  const float* Wo = (const float*)d_in[13];
  const float* bo = (const float*)d_in[14];
  const float* rel = (const float*)d_in[15];
  const float* ln2_g = (const float*)d_in[16];
  const float* ln2_b = (const float*)d_in[17];
  const float* W1 = (const float*)d_in[18];
  const float* b1 = (const float*)d_in[19];
  const float* W2 = (const float*)d_in[20];
  const float* b2 = (const float*)d_in[21];
  const float* gWq = (const float*)d_in[22];
  const float* gbq = (const float*)d_in[23];
  const float* gWk = (const float*)d_in[24];
  const float* gbk = (const float*)d_in[25];
  const float* gWv = (const float*)d_in[26];
  const float* gbv = (const float*)d_in[27];
  const float* gWo = (const float*)d_in[28];
  const float* gbo = (const float*)d_in[29];
  const float* hW1 = (const float*)d_in[30];
  const float* hb1 = (const float*)d_in[31];
  const float* hlng = (const float*)d_in[32];
  const float* hlnb = (const float*)d_in[33];
  const float* hW2 = (const float*)d_in[34];
  const float* hb2 = (const float*)d_in[35];
  float* out = (float*)d_out;

  uint8_t* wsb = (uint8_t*)d_ws;
  const size_t MB = 1024 * 1024;
  float* h = (float*)(wsb + 0);              // 8 MB
  ushort* xn = (ushort*)(wsb + 8 * MB);      // 4 MB
  ushort* qkvb = (ushort*)(wsb + 12 * MB);   // 12 MB  [4096][1536]
  ushort* kvb = qkvb;                        // final KV [4096][1024] (reuse)
  ushort* aob = (ushort*)(wsb + 24 * MB);    // 4 MB
  ushort* ffb = (ushort*)(wsb + 28 * MB);    // 16 MB  [4096][2048]
  ushort* vTb = ffb;                         // 4 MB, time-shared with ffb
  ushort* wqkv = (ushort*)(wsb + 44 * MB);   // 4 x 1.5 MB
  ushort* wto = (ushort*)(wsb + 50 * MB);    // 4 x 0.5 MB
  ushort* wt1 = (ushort*)(wsb + 52 * MB);    // 4 x 2 MB
  ushort* wt2 = (ushort*)(wsb + 60 * MB);    // 4 x 2 MB
  ushort* gwkv = (ushort*)(wsb + 68 * MB);   // 1 MB (gWk,gWv transposed)
  ushort* relb = (ushort*)(wsb + 70 * MB);   // 40 KB
  float* attnlast = (float*)(wsb + 71 * MB);
  float* ctx = attnlast + 4096;

  const size_t W55 = 512 * 512;

  // ---- upfront weight prep ----
  {
    PJobs j{};
    for (int l = 0; l < 4; l++) {
      j.s[l * 4 + 0] = Wq + (size_t)l * W55;
      j.d[l * 4 + 0] = wqkv + (size_t)l * 1536 * 512;
      j.s[l * 4 + 1] = Wk + (size_t)l * W55;
      j.d[l * 4 + 1] = wqkv + (size_t)l * 1536 * 512 + 512 * 512;
      j.s[l * 4 + 2] = Wv + (size_t)l * W55;
      j.d[l * 4 + 2] = wqkv + (size_t)l * 1536 * 512 + 1024 * 512;
      j.s[l * 4 + 3] = Wo + (size_t)l * W55;
      j.d[l * 4 + 3] = wto + (size_t)l * W55;
    }
    j.s[16] = gWk; j.d[16] = gwkv;
    j.s[17] = gWv; j.d[17] = gwkv + 512 * 512;
    k_wprep<<<dim3(16, 16, 18), 256, 0, stream>>>(j, 512, 512);
  }
  {
    PJobs j{};
    for (int l = 0; l < 4; l++) {
      j.s[l] = W1 + (size_t)l * 512 * 2048;
      j.d[l] = wt1 + (size_t)l * 2048 * 512;
    }
    k_wprep<<<dim3(64, 16, 4), 256, 0, stream>>>(j, 512, 2048);
  }
  {
    PJobs j{};
    for (int l = 0; l < 4; l++) {
      j.s[l] = W2 + (size_t)l * 2048 * 512;
      j.d[l] = wt2 + (size_t)l * 512 * 2048;
    }
    k_wprep<<<dim3(16, 64, 4), 256, 0, stream>>>(j, 2048, 512);
  }
  k_relprep<<<dim3(20, 4), 256, 0, stream>>>(rel, relb);
  // input projection with fused layer-0 ln1 -> writes h AND xn
  k_inproj<<<1024, 256, 0, stream>>>(x, in_W, in_b, in_lng, in_lnb,
                                     ln1_g, ln1_b, h, xn);

  for (int l = 0; l < 4; l++) {
    size_t vo = (size_t)l * 512;
    if (l > 0) k_lnw<<<1024, 256, 0, stream>>>(h, ln1_g + vo, ln1_b + vo, xn);
    // fused QKV (V written only as V^T into vTb)
    k_mg<128, 64, 0, 1><<<768, 256, 0, stream>>>(xn, wqkv + (size_t)l * 1536 * 512,
                                                 bq + vo, bk + vo, bv + vo, qkvb,
                                                 vTb, 512, 1536, 24);
    k_attn3<<<512, 256, 0, stream>>>(qkvb, vTb, relb + (size_t)l * 80 * 64, aob);
    k_mg<64, 64, 1, 0><<<512, 256, 0, stream>>>(aob, wto + (size_t)l * W55, bo + vo,
                                                nullptr, nullptr, h, nullptr, 512, 512, 8);
    k_lnw<<<1024, 256, 0, stream>>>(h, ln2_g + vo, ln2_b + vo, xn);
    k_mg<128, 128, 2, 0><<<512, 256, 0, stream>>>(xn, wt1 + (size_t)l * 2048 * 512,
                                                  b1 + (size_t)l * 2048, nullptr, nullptr,
                                                  ffb, nullptr, 512, 2048, 16);
    if (l < 3)
      k_mg<64, 64, 1, 0><<<512, 256, 0, stream>>>(ffb, wt2 + (size_t)l * 512 * 2048,
                                                  b2 + vo, nullptr, nullptr, h, nullptr,
                                                  2048, 512, 8);
    else
      k_mg<64, 64, 3, 0><<<512, 256, 0, stream>>>(ffb, wt2 + (size_t)l * 512 * 2048,
                                                  b2 + vo, nullptr, nullptr, h, xn,
                                                  2048, 512, 8);
  }

  // final global attention: KV-only GEMM + in-kernel Q
  k_mg<128, 64, 0, 2><<<512, 256, 0, stream>>>(xn, gwkv, gbk, gbv, nullptr, kvb,
                                               nullptr, 512, 1024, 16);
  k_gattn2<<<32, 256, 0, stream>>>(xn, gWq, gbq, kvb, attnlast);
  k_rowgemm<<<64, 256, 0, stream>>>(attnlast, gWo, gbo, ctx);
  k_head<<<12, 512, 0, stream>>>(ctx, hW1, hb1, hlng, hlnb, hW2, hb2, out);
}